// Round 20
// baseline (142.405 us; speedup 1.0000x reference)
//
#include <hip/hip_runtime.h>
#include <stdint.h>

typedef unsigned short u16;
typedef __attribute__((ext_vector_type(8))) __bf16 bf16x8;
typedef __attribute__((ext_vector_type(4))) float f32x4;
typedef __attribute__((ext_vector_type(16))) float f32x16;

__device__ __forceinline__ u16 f2bf(float f) {
  union { float f; uint32_t u; } c; c.f = f;
  uint32_t u = c.u + 0x7fffu + ((c.u >> 16) & 1u);
  return (u16)(u >> 16);
}
__device__ __forceinline__ float bf2f(uint32_t v) {
  union { uint32_t u; float f; } c; c.u = v << 16; return c.f;
}
__device__ __forceinline__ uint32_t cvtpk(float a, float b) {
  uint32_t r;
  asm("v_cvt_pk_bf16_f32 %0, %1, %2" : "=v"(r) : "v"(a), "v"(b));
  return r;
}

__device__ __forceinline__ void async16(const u16* g, u16* l) {
  __builtin_amdgcn_global_load_lds(
      (const __attribute__((address_space(1))) void*)g,
      (__attribute__((address_space(3))) void*)l, 16, 0, 0);
}

__device__ __forceinline__ f32x4 mfma16(bf16x8 a, bf16x8 b, f32x4 c) {
  return __builtin_amdgcn_mfma_f32_16x16x32_bf16(a, b, c, 0, 0, 0);
}
__device__ __forceinline__ f32x16 mfma32(bf16x8 a, bf16x8 b, f32x16 c) {
  return __builtin_amdgcn_mfma_f32_32x32x16_bf16(a, b, c, 0, 0, 0);
}

// ---------------- conversion kernels ----------------

__global__ __launch_bounds__(256) void x_cvt_kernel(const float* __restrict__ x,
                                                    u16* __restrict__ xb) {
  int i = (blockIdx.x * 256 + threadIdx.x) * 4;
  float4 v = *(const float4*)(x + i);
  uint2 t; t.x = cvtpk(v.x, v.y); t.y = cvtpk(v.z, v.w);
  *(uint2*)(xb + i) = t;
}

// W [K=1024][N=1024] fp32  ->  WT [N][K] bf16
__global__ __launch_bounds__(256) void wt_cvt_kernel(const float* __restrict__ Wq,
                                                     const float* __restrict__ Wk,
                                                     const float* __restrict__ Wv,
                                                     const float* __restrict__ Wo,
                                                     u16* __restrict__ out) {
  __shared__ __align__(16) u16 t[64][72];
  int z = blockIdx.z;
  const float* W = (z == 0) ? Wq : (z == 1) ? Wk : (z == 2) ? Wv : Wo;
  u16* o = out + (size_t)z * (1u << 20);
  int n0 = blockIdx.x * 64, k0 = blockIdx.y * 64;
  int tid = threadIdx.x;
  int c4 = (tid & 15) * 4, r0 = tid >> 4;
#pragma unroll
  for (int i = 0; i < 4; i++) {
    int r = r0 + i * 16;
    float4 v = *(const float4*)(W + (size_t)(k0 + r) * 1024 + n0 + c4);
    t[c4 + 0][r] = f2bf(v.x);
    t[c4 + 1][r] = f2bf(v.y);
    t[c4 + 2][r] = f2bf(v.z);
    t[c4 + 3][r] = f2bf(v.w);
  }
  __syncthreads();
  int n = tid >> 2, kc = (tid & 3) * 16;
  uint4 a = *(const uint4*)&t[n][kc];
  uint4 b = *(const uint4*)&t[n][kc + 8];
  *(uint4*)(o + (size_t)(n0 + n) * 1024 + k0 + kc) = a;
  *(uint4*)(o + (size_t)(n0 + n) * 1024 + k0 + kc + 8) = b;
}

// ------------- GEMM core v4: DEPTH-3 counted-vmcnt pipeline ----------------
template <int TN>
__device__ __forceinline__ void gemm_core3(const u16* __restrict__ A,
                                           const u16* __restrict__ Bt,
                                           u16* As, u16* Bs,
                                           f32x4 (&acc)[4][TN / 32],
                                           int m0, int n0) {
  constexpr int NJ = TN / 32;
  constexpr int ASZ = 128 * 32, BSZ = TN * 32;
  const int tid = threadIdx.x, wave = tid >> 6, lane = tid & 63;
  const int low = lane & 15, hi = lane >> 4;
  const int wm = wave >> 1, wn = wave & 1;
  const f32x4 fzero = {0.f, 0.f, 0.f, 0.f};
#pragma unroll
  for (int i = 0; i < 4; i++)
#pragma unroll
    for (int j = 0; j < NJ; j++) acc[i][j] = fzero;

  const int ea0 = wave * 128 + lane, ea1 = ea0 + 64;
  const u16* ga0 = A + (size_t)(m0 + (ea0 >> 2)) * 1024 + (ea0 & 3) * 8;
  const u16* ga1 = A + (size_t)(m0 + (ea1 >> 2)) * 1024 + (ea1 & 3) * 8;
  u16* la0 = As + (wave * 2 + 0) * 512;
  u16* la1 = As + (wave * 2 + 1) * 512;

  const int eb0 = (TN == 128) ? (wave * 128 + lane) : (wave * 64 + lane);
  const int eb1 = eb0 + 64;
  const u16* gb0 = Bt + (size_t)(n0 + (eb0 >> 2)) * 1024 + (eb0 & 3) * 8;
  const u16* gb1 = Bt + (size_t)(n0 + (eb1 >> 2)) * 1024 + (eb1 & 3) * 8;
  u16* lb0 = Bs + ((TN == 128) ? (wave * 2 + 0) * 512 : wave * 512);
  u16* lb1 = Bs + (wave * 2 + 1) * 512;

  const u16* ap = As + (wm * 64 + low) * 32 + hi * 8;
  const u16* bp = Bs + (wn * (TN / 2) + low) * 32 + hi * 8;

#define GSTAGE(buf, KT)                                                        \
  {                                                                            \
    async16(ga0 + (KT), la0 + (buf) * ASZ);                                    \
    async16(ga1 + (KT), la1 + (buf) * ASZ);                                    \
    async16(gb0 + (KT), lb0 + (buf) * BSZ);                                    \
    if (TN == 128) async16(gb1 + (KT), lb1 + (buf) * BSZ);                     \
  }

  GSTAGE(0, 0)
  GSTAGE(1, 32)
  GSTAGE(2, 64)
  int buf = 0;
  for (int kt = 0; kt < 1024; kt += 32) {
    if (kt + 96 <= 1024) {
      if constexpr (TN == 128) asm volatile("s_waitcnt vmcnt(8)" ::: "memory");
      else                     asm volatile("s_waitcnt vmcnt(6)" ::: "memory");
    } else if (kt + 64 <= 1024) {
      if constexpr (TN == 128) asm volatile("s_waitcnt vmcnt(4)" ::: "memory");
      else                     asm volatile("s_waitcnt vmcnt(3)" ::: "memory");
    } else {
      asm volatile("s_waitcnt vmcnt(0)" ::: "memory");
    }
    __builtin_amdgcn_s_barrier();

    bf16x8 af[4], bfv[NJ];
#pragma unroll
    for (int i = 0; i < 4; i++)
      af[i] = *(const bf16x8*)(ap + buf * ASZ + i * 16 * 32);
#pragma unroll
    for (int j = 0; j < NJ; j++)
      bfv[j] = *(const bf16x8*)(bp + buf * BSZ + j * 16 * 32);
#pragma unroll
    for (int i = 0; i < 4; i++)
#pragma unroll
      for (int j = 0; j < NJ; j++) acc[i][j] = mfma16(af[i], bfv[j], acc[i][j]);

    __builtin_amdgcn_s_barrier();
    if (kt + 96 < 1024) GSTAGE(buf, kt + 96)
    buf = (buf == 2) ? 0 : buf + 1;
  }
#undef GSTAGE
}

// QKV projection, XCD-chunked flat grid of 768 blocks.
__global__ __launch_bounds__(256) void gemm_qkv_kernel(
    const u16* __restrict__ xb, const u16* __restrict__ wT,
    const float* __restrict__ bq, const float* __restrict__ bk,
    const float* __restrict__ bv,
    u16* __restrict__ qs, u16* __restrict__ ks, u16* __restrict__ vts) {
  __shared__ __align__(16) u16 smem[24576];
  u16* As = smem;
  u16* Bs = smem + 12288;

  const int bid = blockIdx.x;
  const int c = bid & 7;
  const int j = bid >> 3;
  const int z = j >> 5;
  const int jj = j & 31;
  const int ytile = (c >> 1) * 8 + (jj >> 2);
  const int xtile = (c & 1) * 4 + (jj & 3);
  const int m0 = ytile * 128, n0 = xtile * 128;

  const u16* Bt = wT + (size_t)z * (1u << 20);
  f32x4 acc[4][4];
  gemm_core3<128>(xb, Bt, As, Bs, acc, m0, n0);

  const float* bias = (z == 0) ? bq : (z == 1) ? bk : bv;
  u16* out = (z == 0) ? qs : (z == 1) ? ks : vts;
  const float scale = (z == 0) ? 0.180336880f : 1.0f;
  const int tid = threadIdx.x, wave = tid >> 6, lane = tid & 63;
  const int low = lane & 15, hi = lane >> 4;
  const int wm = wave >> 1, wn = wave & 1;

  const int h = (n0 >> 6) + wn;
  const int gmb = m0 + wm * 64;
  const int b = gmb >> 11;
  const int lb = gmb & 2047;

  u16* tile = smem + wave * 4360;
#pragma unroll
  for (int i = 0; i < 4; i++)
#pragma unroll
    for (int jx = 0; jx < 4; jx++) {
      int hd = jx * 16 + low;
      float bval = bias[h * 64 + hd];
#pragma unroll
      for (int r = 0; r < 4; r++) {
        int row = i * 16 + hi * 4 + r;
        tile[row * 68 + hd] = f2bf((acc[i][jx][r] + bval) * scale);
      }
    }

  if (z != 2) {
    u16* dst = out + ((size_t)((b * 16 + h) * 2048 + lb + lane)) * 64;
    const u16* src = tile + lane * 68;
#pragma unroll
    for (int cc = 0; cc < 4; cc++) {
      uint2 a0 = *(const uint2*)(src + cc * 16 + 0);
      uint2 a1 = *(const uint2*)(src + cc * 16 + 4);
      uint2 a2 = *(const uint2*)(src + cc * 16 + 8);
      uint2 a3 = *(const uint2*)(src + cc * 16 + 12);
      uint4 w0; w0.x = a0.x; w0.y = a0.y; w0.z = a1.x; w0.w = a1.y;
      uint4 w1; w1.x = a2.x; w1.y = a2.y; w1.z = a3.x; w1.w = a3.y;
      *(uint4*)(dst + cc * 16 + 0) = w0;
      *(uint4*)(dst + cc * 16 + 8) = w1;
    }
  } else {
    int l4 = (lane & 15) * 4;
    int lp4 = (l4 & ~12) | ((l4 & 4) << 1) | ((l4 & 8) >> 1);
    int ghd = lane >> 4;
    u16* vbase = out + ((size_t)(b * 16 + h) * 64) * 2048 + lb + lp4;
#pragma unroll
    for (int s = 0; s < 16; s++) {
      int hd = s * 4 + ghd;
      uint32_t v0 = tile[(l4 + 0) * 68 + hd];
      uint32_t v1 = tile[(l4 + 1) * 68 + hd];
      uint32_t v2 = tile[(l4 + 2) * 68 + hd];
      uint32_t v3 = tile[(l4 + 3) * 68 + hd];
      uint2 w; w.x = v0 | (v1 << 16); w.y = v2 | (v3 << 16);
      *(uint2*)(vbase + (size_t)hd * 2048) = w;
    }
  }
}

// output projection: XCD-chunked flat grid of 512 blocks (128x64 tiles)
__global__ __launch_bounds__(256) void gemm_out_kernel(
    const u16* __restrict__ ctx, const u16* __restrict__ woT,
    const float* __restrict__ bo, float* __restrict__ out) {
  __shared__ __align__(16) u16 As[3 * 128 * 32];
  __shared__ __align__(16) u16 Bs[3 * 64 * 32];

  const int bid = blockIdx.x;
  const int c = bid & 7;
  const int j = bid >> 3;
  const int ytile = (c >> 1) * 8 + (j >> 3);
  const int xtile = (c & 1) * 8 + (j & 7);
  const int m0 = ytile * 128, n0 = xtile * 64;

  f32x4 acc[4][2];
  gemm_core3<64>(ctx, woT, As, Bs, acc, m0, n0);
  const int tid = threadIdx.x, wave = tid >> 6, lane = tid & 63;
  const int low = lane & 15, hi = lane >> 4;
  const int wm = wave >> 1, wn = wave & 1;
#pragma unroll
  for (int i = 0; i < 4; i++)
#pragma unroll
    for (int jx = 0; jx < 2; jx++) {
      int gn = n0 + wn * 32 + jx * 16 + low;
      float bval = bo[gn];
#pragma unroll
      for (int r = 0; r < 4; r++) {
        int gm = m0 + wm * 64 + i * 16 + hi * 4 + r;
        out[(size_t)gm * 1024 + gn] = acc[i][jx][r] + bval;
      }
    }
}

// ---------------- flash attention v16: K-only LDS, V direct-global --------
// 512 blocks x 512 threads, KV-split groups (g=0: tiles [0,nT), g=1:
// [nT,2nT)). ONLY K is staged in LDS (double-buffered, 32 KB total);
// V fragments are read directly from global, issued at the TOP of the
// compute phase and consumed ~800cy later in PV (QK^T + softmax in
// between) -> L1/L2 latency hidden. V addresses are identical across all
// 8 waves -> L1 broadcast. Counted vmcnt(2) (2 K-loads/wave/stage; plain
// V loads are compiler-waited before PV, retired before next tile top).
// Scalar l_ (no lacc) to keep VGPR <= 85 -> target 3 blocks/CU.
// 2-way merge via bf16-packed LDS scratch (18.4 KB, overlays Kls).
__global__ __launch_bounds__(512) void flash_kernel(
    const u16* __restrict__ Qs, const u16* __restrict__ Ks,
    const u16* __restrict__ Vts, u16* __restrict__ ctx) {
  __shared__ __align__(16) u16 Kls[2][2][64 * 64];  // 32 KB

  const int bid = blockIdx.x;
  const int qt = (bid < 256) ? (15 - (bid >> 5)) : ((bid - 256) >> 5);
  const int bh = bid & 31;
  const int qb = qt * 128;
  const int nT = qt + 1;

  const int tid = threadIdx.x, wave = tid >> 6, lane = tid & 63;
  const int wq = wave & 3, g = wave >> 2;
  const int q32 = lane & 31, hi2 = lane >> 5;
  const int x7 = q32 & 7;

  const u16* Qb = Qs + (size_t)bh * (2048 * 64);
  const u16* Kb = Ks + (size_t)bh * (2048 * 64);
  const u16* Vb = Vts + (size_t)bh * (64 * 2048);

  const int qrow = qb + wq * 32 + q32;
  bf16x8 qf[4];
#pragma unroll
  for (int ds = 0; ds < 4; ds++)
    qf[ds] = *(const bf16x8*)(Qb + (size_t)qrow * 64 + ds * 16 + hi2 * 8);

  f32x16 o0, o1;
#pragma unroll
  for (int r = 0; r < 16; r++) { o0[r] = 0.f; o1[r] = 0.f; }
  float m_ = -1e30f, l_ = 0.f;

#define STAGE(buf, KT0)                                                        \
  {                                                                            \
    _Pragma("unroll") for (int i = 0; i < 2; i++) {                            \
      int row = (wq * 2 + i) * 8 + (lane >> 3);                                \
      async16(Kb + (size_t)((KT0) + row) * 64 +                                \
                  (((lane & 7) ^ (row & 7)) * 8),                              \
              &Kls[g][buf][(wq * 2 + i) * 512]);                               \
    }                                                                          \
  }

  const int tb = g * nT;
  STAGE(0, (tb + 0) * 64)
  STAGE(1, (tb + 1) * 64)

  const int qmax = qb + wq * 32 + 31;
  const u16* vG0 = Vb + (size_t)q32 * 2048;
  const u16* vG1 = Vb + (size_t)(32 + q32) * 2048;

  int cur = 0;
  for (int t = 0; t < nT; t++) {
    const int kt0 = (tb + t) * 64;
    if (t + 1 < nT) { asm volatile("s_waitcnt vmcnt(2)" ::: "memory"); }
    else            { asm volatile("s_waitcnt vmcnt(0)" ::: "memory"); }
    __builtin_amdgcn_s_barrier();

    if (kt0 <= qmax) {
      const u16* Kc = &Kls[g][cur][0];

      // ---- V fragments from GLOBAL, issued first (hidden under QK^T) ----
      bf16x8 vf0[4], vf1[4];
#pragma unroll
      for (int ksx = 0; ksx < 4; ksx++) {
        int sc = (2 * ksx + hi2) * 8;
        vf0[ksx] = *(const bf16x8*)(vG0 + kt0 + sc);
        vf1[ksx] = *(const bf16x8*)(vG1 + kt0 + sc);
      }

      // ---- QK^T from LDS ----
      f32x16 s0, s1;
#pragma unroll
      for (int r = 0; r < 16; r++) { s0[r] = 0.f; s1[r] = 0.f; }
      __builtin_amdgcn_s_setprio(1);
#pragma unroll
      for (int ds = 0; ds < 4; ds++) {
        int cs = ((ds * 2 + hi2) ^ x7) * 8;
        bf16x8 kf0 = *(const bf16x8*)(Kc + q32 * 64 + cs);
        bf16x8 kf1 = *(const bf16x8*)(Kc + (32 + q32) * 64 + cs);
        s0 = mfma32(kf0, qf[ds], s0);
        s1 = mfma32(kf1, qf[ds], s1);
      }
      __builtin_amdgcn_s_setprio(0);

      // ---- causal mask ----
      if (kt0 + 63 > qb + wq * 32) {
#pragma unroll
        for (int r = 0; r < 16; r++) {
          int kl = (r & 3) + 8 * (r >> 2) + 4 * hi2;
          if (kt0 + kl > qrow) s0[r] = -1e30f;
          if (kt0 + 32 + kl > qrow) s1[r] = -1e30f;
        }
      }

      // ---- lazy max: lane-local trigger, shfl only when tripped ----
      float lpm = -1e30f;
#pragma unroll
      for (int r = 0; r < 16; r++) lpm = fmaxf(lpm, fmaxf(s0[r], s1[r]));
      if (__any(lpm > m_ + 8.f)) {
        float pm = fmaxf(lpm, __shfl_xor(lpm, 32));
        float mn = fmaxf(m_, pm);
        float corr = __builtin_amdgcn_exp2f(m_ - mn);
        m_ = mn;
        l_ *= corr;
#pragma unroll
        for (int r = 0; r < 16; r++) { o0[r] *= corr; o1[r] *= corr; }
      }

      // ---- exp2 + row sum ----
      float rs = 0.f;
#pragma unroll
      for (int r = 0; r < 16; r++) {
        s0[r] = __builtin_amdgcn_exp2f(s0[r] - m_);
        s1[r] = __builtin_amdgcn_exp2f(s1[r] - m_);
        rs += s0[r] + s1[r];
      }
      rs += __shfl_xor(rs, 32);
      l_ += rs;

      // ---- P fragments ----
      bf16x8 pb[4];
#pragma unroll
      for (int ksx = 0; ksx < 4; ksx++) {
        union { uint32_t u[4]; bf16x8 v; } pu;
        if (ksx < 2) {
          int rb = 8 * ksx;
          pu.u[0] = cvtpk(s0[rb + 0], s0[rb + 1]);
          pu.u[1] = cvtpk(s0[rb + 2], s0[rb + 3]);
          pu.u[2] = cvtpk(s0[rb + 4], s0[rb + 5]);
          pu.u[3] = cvtpk(s0[rb + 6], s0[rb + 7]);
        } else {
          int rb = 8 * (ksx - 2);
          pu.u[0] = cvtpk(s1[rb + 0], s1[rb + 1]);
          pu.u[1] = cvtpk(s1[rb + 2], s1[rb + 3]);
          pu.u[2] = cvtpk(s1[rb + 4], s1[rb + 5]);
          pu.u[3] = cvtpk(s1[rb + 6], s1[rb + 7]);
        }
        pb[ksx] = pu.v;
      }

      // ---- PV (compiler waits V loads here) ----
      __builtin_amdgcn_s_setprio(1);
#pragma unroll
      for (int ksx = 0; ksx < 4; ksx++) {
        o0 = mfma32(vf0[ksx], pb[ksx], o0);
        o1 = mfma32(vf1[ksx], pb[ksx], o1);
      }
      __builtin_amdgcn_s_setprio(0);
    }

    __builtin_amdgcn_s_barrier();
    if (t + 2 < nT) STAGE(cur, (tb + t + 2) * 64)
    cur ^= 1;
  }

  // ---- merge group 1 into group 0 via bf16-packed LDS scratch ----
  __syncthreads();
  uint32_t* sc32 = (uint32_t*)&Kls[0][0][0];
  uint32_t* mb = sc32 + wq * 1152 + lane * 16;
  float* mlf = (float*)(sc32 + wq * 1152 + 1024);
  if (g == 1) {
#pragma unroll
    for (int m = 0; m < 4; m++) {
      mb[2 * m + 0] = cvtpk(o0[4 * m + 0], o0[4 * m + 1]);
      mb[2 * m + 1] = cvtpk(o0[4 * m + 2], o0[4 * m + 3]);
      mb[8 + 2 * m + 0] = cvtpk(o1[4 * m + 0], o1[4 * m + 1]);
      mb[8 + 2 * m + 1] = cvtpk(o1[4 * m + 2], o1[4 * m + 3]);
    }
    mlf[(lane << 1) + 0] = m_;
    mlf[(lane << 1) + 1] = l_;
  }
  __syncthreads();
  if (g == 0) {
    float m1 = mlf[(lane << 1) + 0];
    float l1 = mlf[(lane << 1) + 1];
    float mm = fmaxf(m_, m1);
    float cA = __builtin_amdgcn_exp2f(m_ - mm);
    float cB = __builtin_amdgcn_exp2f(m1 - mm);
    l_ = l_ * cA + l1 * cB;
#pragma unroll
    for (int m = 0; m < 4; m++) {
      uint32_t pa0 = mb[2 * m + 0], pa1 = mb[2 * m + 1];
      uint32_t pb0 = mb[8 + 2 * m + 0], pb1 = mb[8 + 2 * m + 1];
      o0[4 * m + 0] = o0[4 * m + 0] * cA + bf2f(pa0 & 0xffffu) * cB;
      o0[4 * m + 1] = o0[4 * m + 1] * cA + bf2f(pa0 >> 16) * cB;
      o0[4 * m + 2] = o0[4 * m + 2] * cA + bf2f(pa1 & 0xffffu) * cB;
      o0[4 * m + 3] = o0[4 * m + 3] * cA + bf2f(pa1 >> 16) * cB;
      o1[4 * m + 0] = o1[4 * m + 0] * cA + bf2f(pb0 & 0xffffu) * cB;
      o1[4 * m + 1] = o1[4 * m + 1] * cA + bf2f(pb0 >> 16) * cB;
      o1[4 * m + 2] = o1[4 * m + 2] * cA + bf2f(pb1 & 0xffffu) * cB;
      o1[4 * m + 3] = o1[4 * m + 3] * cA + bf2f(pb1 >> 16) * cB;
    }

    const int b = bh >> 4, h = bh & 15;
    float inv = 1.f / l_;
    size_t base = ((size_t)(b * 2048 + qrow)) * 1024 + h * 64;
#pragma unroll
    for (int m = 0; m < 4; m++) {
      uint2 w0, w1;
      w0.x = cvtpk(o0[4 * m + 0] * inv, o0[4 * m + 1] * inv);
      w0.y = cvtpk(o0[4 * m + 2] * inv, o0[4 * m + 3] * inv);
      *(uint2*)(ctx + base + 8 * m + 4 * hi2) = w0;
      w1.x = cvtpk(o1[4 * m + 0] * inv, o1[4 * m + 1] * inv);
      w1.y = cvtpk(o1[4 * m + 2] * inv, o1[4 * m + 3] * inv);
      *(uint2*)(ctx + base + 32 + 8 * m + 4 * hi2) = w1;
    }
  }
}

// ---------------- launch ----------------

extern "C" void kernel_launch(void* const* d_in, const int* in_sizes, int n_in,
                              void* d_out, int out_size, void* d_ws, size_t ws_size,
                              hipStream_t stream) {
  const float* x  = (const float*)d_in[0];
  const float* Wq = (const float*)d_in[1];
  const float* bq = (const float*)d_in[2];
  const float* Wk = (const float*)d_in[3];
  const float* bk = (const float*)d_in[4];
  const float* Wv = (const float*)d_in[5];
  const float* bv = (const float*)d_in[6];
  const float* Wo = (const float*)d_in[7];
  const float* bo = (const float*)d_in[8];

  char* ws = (char*)d_ws;
  u16* xb  = (u16*)(ws);                    // [4096][1024] bf16, 8MB
  u16* wT  = (u16*)(ws + (8u << 20));       // 4 x [1024][1024] bf16, 8MB
  u16* qs  = (u16*)(ws + (16u << 20));      // [32][2048][64] bf16 (pre-scaled)
  u16* ks  = (u16*)(ws + (24u << 20));      // [32][2048][64] bf16
  u16* vts = (u16*)(ws + (32u << 20));      // [32][64][2048] bf16 (k-permuted)
  u16* ctx = (u16*)(ws + (40u << 20));      // [4096][1024] bf16

  x_cvt_kernel<<<4096, 256, 0, stream>>>(x, xb);
  wt_cvt_kernel<<<dim3(16, 16, 4), 256, 0, stream>>>(Wq, Wk, Wv, Wo, wT);
  gemm_qkv_kernel<<<768, 256, 0, stream>>>(xb, wT, bq, bk, bv, qs, ks, vts);
  flash_kernel<<<512, 512, 0, stream>>>(qs, ks, vts, ctx);
  gemm_out_kernel<<<512, 256, 0, stream>>>(ctx, wT + 3 * (1u << 20), bo, (float*)d_out);
}

// Round 21
// 117.985 us; speedup vs baseline: 1.2070x; 1.2070x over previous
//
#include <hip/hip_runtime.h>
#include <stdint.h>

typedef unsigned short u16;
typedef __attribute__((ext_vector_type(8))) __bf16 bf16x8;
typedef __attribute__((ext_vector_type(4))) float f32x4;
typedef __attribute__((ext_vector_type(16))) float f32x16;

__device__ __forceinline__ u16 f2bf(float f) {
  union { float f; uint32_t u; } c; c.f = f;
  uint32_t u = c.u + 0x7fffu + ((c.u >> 16) & 1u);
  return (u16)(u >> 16);
}
__device__ __forceinline__ uint32_t cvtpk(float a, float b) {
  uint32_t r;
  asm("v_cvt_pk_bf16_f32 %0, %1, %2" : "=v"(r) : "v"(a), "v"(b));
  return r;
}

__device__ __forceinline__ void async16(const u16* g, u16* l) {
  __builtin_amdgcn_global_load_lds(
      (const __attribute__((address_space(1))) void*)g,
      (__attribute__((address_space(3))) void*)l, 16, 0, 0);
}

__device__ __forceinline__ f32x4 mfma16(bf16x8 a, bf16x8 b, f32x4 c) {
  return __builtin_amdgcn_mfma_f32_16x16x32_bf16(a, b, c, 0, 0, 0);
}
__device__ __forceinline__ f32x16 mfma32(bf16x8 a, bf16x8 b, f32x16 c) {
  return __builtin_amdgcn_mfma_f32_32x32x16_bf16(a, b, c, 0, 0, 0);
}

// ---------------- conversion kernels ----------------

__global__ __launch_bounds__(256) void x_cvt_kernel(const float* __restrict__ x,
                                                    u16* __restrict__ xb) {
  int i = (blockIdx.x * 256 + threadIdx.x) * 4;
  float4 v = *(const float4*)(x + i);
  uint2 t; t.x = cvtpk(v.x, v.y); t.y = cvtpk(v.z, v.w);
  *(uint2*)(xb + i) = t;
}

// W [K=1024][N=1024] fp32  ->  WT [N][K] bf16
__global__ __launch_bounds__(256) void wt_cvt_kernel(const float* __restrict__ Wq,
                                                     const float* __restrict__ Wk,
                                                     const float* __restrict__ Wv,
                                                     const float* __restrict__ Wo,
                                                     u16* __restrict__ out) {
  __shared__ __align__(16) u16 t[64][72];
  int z = blockIdx.z;
  const float* W = (z == 0) ? Wq : (z == 1) ? Wk : (z == 2) ? Wv : Wo;
  u16* o = out + (size_t)z * (1u << 20);
  int n0 = blockIdx.x * 64, k0 = blockIdx.y * 64;
  int tid = threadIdx.x;
  int c4 = (tid & 15) * 4, r0 = tid >> 4;
#pragma unroll
  for (int i = 0; i < 4; i++) {
    int r = r0 + i * 16;
    float4 v = *(const float4*)(W + (size_t)(k0 + r) * 1024 + n0 + c4);
    t[c4 + 0][r] = f2bf(v.x);
    t[c4 + 1][r] = f2bf(v.y);
    t[c4 + 2][r] = f2bf(v.z);
    t[c4 + 3][r] = f2bf(v.w);
  }
  __syncthreads();
  int n = tid >> 2, kc = (tid & 3) * 16;
  uint4 a = *(const uint4*)&t[n][kc];
  uint4 b = *(const uint4*)&t[n][kc + 8];
  *(uint4*)(o + (size_t)(n0 + n) * 1024 + k0 + kc) = a;
  *(uint4*)(o + (size_t)(n0 + n) * 1024 + k0 + kc + 8) = b;
}

// ------------- GEMM core v4: DEPTH-3 counted-vmcnt pipeline ----------------
template <int TN>
__device__ __forceinline__ void gemm_core3(const u16* __restrict__ A,
                                           const u16* __restrict__ Bt,
                                           u16* As, u16* Bs,
                                           f32x4 (&acc)[4][TN / 32],
                                           int m0, int n0) {
  constexpr int NJ = TN / 32;
  constexpr int ASZ = 128 * 32, BSZ = TN * 32;
  const int tid = threadIdx.x, wave = tid >> 6, lane = tid & 63;
  const int low = lane & 15, hi = lane >> 4;
  const int wm = wave >> 1, wn = wave & 1;
  const f32x4 fzero = {0.f, 0.f, 0.f, 0.f};
#pragma unroll
  for (int i = 0; i < 4; i++)
#pragma unroll
    for (int j = 0; j < NJ; j++) acc[i][j] = fzero;

  const int ea0 = wave * 128 + lane, ea1 = ea0 + 64;
  const u16* ga0 = A + (size_t)(m0 + (ea0 >> 2)) * 1024 + (ea0 & 3) * 8;
  const u16* ga1 = A + (size_t)(m0 + (ea1 >> 2)) * 1024 + (ea1 & 3) * 8;
  u16* la0 = As + (wave * 2 + 0) * 512;
  u16* la1 = As + (wave * 2 + 1) * 512;

  const int eb0 = (TN == 128) ? (wave * 128 + lane) : (wave * 64 + lane);
  const int eb1 = eb0 + 64;
  const u16* gb0 = Bt + (size_t)(n0 + (eb0 >> 2)) * 1024 + (eb0 & 3) * 8;
  const u16* gb1 = Bt + (size_t)(n0 + (eb1 >> 2)) * 1024 + (eb1 & 3) * 8;
  u16* lb0 = Bs + ((TN == 128) ? (wave * 2 + 0) * 512 : wave * 512);
  u16* lb1 = Bs + (wave * 2 + 1) * 512;

  const u16* ap = As + (wm * 64 + low) * 32 + hi * 8;
  const u16* bp = Bs + (wn * (TN / 2) + low) * 32 + hi * 8;

#define GSTAGE(buf, KT)                                                        \
  {                                                                            \
    async16(ga0 + (KT), la0 + (buf) * ASZ);                                    \
    async16(ga1 + (KT), la1 + (buf) * ASZ);                                    \
    async16(gb0 + (KT), lb0 + (buf) * BSZ);                                    \
    if (TN == 128) async16(gb1 + (KT), lb1 + (buf) * BSZ);                     \
  }

  GSTAGE(0, 0)
  GSTAGE(1, 32)
  GSTAGE(2, 64)
  int buf = 0;
  for (int kt = 0; kt < 1024; kt += 32) {
    if (kt + 96 <= 1024) {
      if constexpr (TN == 128) asm volatile("s_waitcnt vmcnt(8)" ::: "memory");
      else                     asm volatile("s_waitcnt vmcnt(6)" ::: "memory");
    } else if (kt + 64 <= 1024) {
      if constexpr (TN == 128) asm volatile("s_waitcnt vmcnt(4)" ::: "memory");
      else                     asm volatile("s_waitcnt vmcnt(3)" ::: "memory");
    } else {
      asm volatile("s_waitcnt vmcnt(0)" ::: "memory");
    }
    __builtin_amdgcn_s_barrier();

    bf16x8 af[4], bfv[NJ];
#pragma unroll
    for (int i = 0; i < 4; i++)
      af[i] = *(const bf16x8*)(ap + buf * ASZ + i * 16 * 32);
#pragma unroll
    for (int j = 0; j < NJ; j++)
      bfv[j] = *(const bf16x8*)(bp + buf * BSZ + j * 16 * 32);
#pragma unroll
    for (int i = 0; i < 4; i++)
#pragma unroll
      for (int j = 0; j < NJ; j++) acc[i][j] = mfma16(af[i], bfv[j], acc[i][j]);

    __builtin_amdgcn_s_barrier();
    if (kt + 96 < 1024) GSTAGE(buf, kt + 96)
    buf = (buf == 2) ? 0 : buf + 1;
  }
#undef GSTAGE
}

// QKV projection, XCD-chunked flat grid of 768 blocks.
__global__ __launch_bounds__(256) void gemm_qkv_kernel(
    const u16* __restrict__ xb, const u16* __restrict__ wT,
    const float* __restrict__ bq, const float* __restrict__ bk,
    const float* __restrict__ bv,
    u16* __restrict__ qs, u16* __restrict__ ks, u16* __restrict__ vts) {
  __shared__ __align__(16) u16 smem[24576];
  u16* As = smem;
  u16* Bs = smem + 12288;

  const int bid = blockIdx.x;
  const int c = bid & 7;
  const int j = bid >> 3;
  const int z = j >> 5;
  const int jj = j & 31;
  const int ytile = (c >> 1) * 8 + (jj >> 2);
  const int xtile = (c & 1) * 4 + (jj & 3);
  const int m0 = ytile * 128, n0 = xtile * 128;

  const u16* Bt = wT + (size_t)z * (1u << 20);
  f32x4 acc[4][4];
  gemm_core3<128>(xb, Bt, As, Bs, acc, m0, n0);

  const float* bias = (z == 0) ? bq : (z == 1) ? bk : bv;
  u16* out = (z == 0) ? qs : (z == 1) ? ks : vts;
  const float scale = (z == 0) ? 0.180336880f : 1.0f;
  const int tid = threadIdx.x, wave = tid >> 6, lane = tid & 63;
  const int low = lane & 15, hi = lane >> 4;
  const int wm = wave >> 1, wn = wave & 1;

  const int h = (n0 >> 6) + wn;
  const int gmb = m0 + wm * 64;
  const int b = gmb >> 11;
  const int lb = gmb & 2047;

  u16* tile = smem + wave * 4360;
#pragma unroll
  for (int i = 0; i < 4; i++)
#pragma unroll
    for (int jx = 0; jx < 4; jx++) {
      int hd = jx * 16 + low;
      float bval = bias[h * 64 + hd];
#pragma unroll
      for (int r = 0; r < 4; r++) {
        int row = i * 16 + hi * 4 + r;
        tile[row * 68 + hd] = f2bf((acc[i][jx][r] + bval) * scale);
      }
    }

  if (z != 2) {
    u16* dst = out + ((size_t)((b * 16 + h) * 2048 + lb + lane)) * 64;
    const u16* src = tile + lane * 68;
#pragma unroll
    for (int cc = 0; cc < 4; cc++) {
      uint2 a0 = *(const uint2*)(src + cc * 16 + 0);
      uint2 a1 = *(const uint2*)(src + cc * 16 + 4);
      uint2 a2 = *(const uint2*)(src + cc * 16 + 8);
      uint2 a3 = *(const uint2*)(src + cc * 16 + 12);
      uint4 w0; w0.x = a0.x; w0.y = a0.y; w0.z = a1.x; w0.w = a1.y;
      uint4 w1; w1.x = a2.x; w1.y = a2.y; w1.z = a3.x; w1.w = a3.y;
      *(uint4*)(dst + cc * 16 + 0) = w0;
      *(uint4*)(dst + cc * 16 + 8) = w1;
    }
  } else {
    int l4 = (lane & 15) * 4;
    int lp4 = (l4 & ~12) | ((l4 & 4) << 1) | ((l4 & 8) >> 1);
    int ghd = lane >> 4;
    u16* vbase = out + ((size_t)(b * 16 + h) * 64) * 2048 + lb + lp4;
#pragma unroll
    for (int s = 0; s < 16; s++) {
      int hd = s * 4 + ghd;
      uint32_t v0 = tile[(l4 + 0) * 68 + hd];
      uint32_t v1 = tile[(l4 + 1) * 68 + hd];
      uint32_t v2 = tile[(l4 + 2) * 68 + hd];
      uint32_t v3 = tile[(l4 + 3) * 68 + hd];
      uint2 w; w.x = v0 | (v1 << 16); w.y = v2 | (v3 << 16);
      *(uint2*)(vbase + (size_t)hd * 2048) = w;
    }
  }
}

// output projection: XCD-chunked flat grid of 512 blocks (128x64 tiles)
__global__ __launch_bounds__(256) void gemm_out_kernel(
    const u16* __restrict__ ctx, const u16* __restrict__ woT,
    const float* __restrict__ bo, float* __restrict__ out) {
  __shared__ __align__(16) u16 As[3 * 128 * 32];
  __shared__ __align__(16) u16 Bs[3 * 64 * 32];

  const int bid = blockIdx.x;
  const int c = bid & 7;
  const int j = bid >> 3;
  const int ytile = (c >> 1) * 8 + (j >> 3);
  const int xtile = (c & 1) * 8 + (j & 7);
  const int m0 = ytile * 128, n0 = xtile * 64;

  f32x4 acc[4][2];
  gemm_core3<64>(ctx, woT, As, Bs, acc, m0, n0);
  const int tid = threadIdx.x, wave = tid >> 6, lane = tid & 63;
  const int low = lane & 15, hi = lane >> 4;
  const int wm = wave >> 1, wn = wave & 1;
#pragma unroll
  for (int i = 0; i < 4; i++)
#pragma unroll
    for (int jx = 0; jx < 2; jx++) {
      int gn = n0 + wn * 32 + jx * 16 + low;
      float bval = bo[gn];
#pragma unroll
      for (int r = 0; r < 4; r++) {
        int gm = m0 + wm * 64 + i * 16 + hi * 4 + r;
        out[(size_t)gm * 1024 + gn] = acc[i][jx][r] + bval;
      }
    }
}

// ---------------- flash attention v17: K dbuf + V single-buf (48 KB) ------
// 512 blocks x 512 threads, KV-split groups (g=0: tiles [0,nT), g=1:
// [nT,2nT)). K double-buffered (32 KB), V SINGLE-buffered (16 KB) -> 48 KB
// total -> 3 blocks/CU (VGPR ~80 <= 85 allows 6 waves/SIMD). Schedule:
// prologue stages V(0),K(0),K(1); per tile: wait vmcnt(2) (oldest 4 =
// current V+K done; next K stays in flight; 0 on last) -> barrier ->
// compute -> barrier -> stage V(t+1) THEN K(t+2). V(t+1) lands during
// t+1's QK^T+softmax. Lazy-max (lane-local trigger). Scalar l_.
__global__ __launch_bounds__(512) void flash_kernel(
    const u16* __restrict__ Qs, const u16* __restrict__ Ks,
    const u16* __restrict__ Vts, u16* __restrict__ ctx) {
  __shared__ __align__(16) u16 smem[24576];  // 48 KB: K [2g][2buf][4096] + V [2g][4096]

  const int bid = blockIdx.x;
  const int qt = (bid < 256) ? (15 - (bid >> 5)) : ((bid - 256) >> 5);
  const int bh = bid & 31;
  const int qb = qt * 128;
  const int nT = qt + 1;

  const int tid = threadIdx.x, wave = tid >> 6, lane = tid & 63;
  const int wq = wave & 3, g = wave >> 2;
  const int q32 = lane & 31, hi2 = lane >> 5;
  const int x7 = q32 & 7;

  const u16* Qb = Qs + (size_t)bh * (2048 * 64);
  const u16* Kb = Ks + (size_t)bh * (2048 * 64);
  const u16* Vb = Vts + (size_t)bh * (64 * 2048);

  u16* Kg = smem + g * 8192;          // [2 bufs][4096]
  u16* Vg = smem + 16384 + g * 4096;  // [4096]

  const int qrow = qb + wq * 32 + q32;
  bf16x8 qf[4];
#pragma unroll
  for (int ds = 0; ds < 4; ds++)
    qf[ds] = *(const bf16x8*)(Qb + (size_t)qrow * 64 + ds * 16 + hi2 * 8);

  f32x16 o0, o1;
#pragma unroll
  for (int r = 0; r < 16; r++) { o0[r] = 0.f; o1[r] = 0.f; }
  float m_ = -1e30f, l_ = 0.f;

#define STAGE_K(buf, KT0)                                                      \
  {                                                                            \
    _Pragma("unroll") for (int i = 0; i < 2; i++) {                            \
      int row = (wq * 2 + i) * 8 + (lane >> 3);                                \
      async16(Kb + (size_t)((KT0) + row) * 64 +                                \
                  (((lane & 7) ^ (row & 7)) * 8),                              \
              Kg + (buf) * 4096 + (wq * 2 + i) * 512);                         \
    }                                                                          \
  }
#define STAGE_V(KT0)                                                           \
  {                                                                            \
    _Pragma("unroll") for (int i = 0; i < 2; i++) {                            \
      int row = (wq * 2 + i) * 8 + (lane >> 3);                                \
      async16(Vb + (size_t)row * 2048 + (KT0) +                                \
                  (((lane & 7) ^ (row & 7)) * 8),                              \
              Vg + (wq * 2 + i) * 512);                                        \
    }                                                                          \
  }

  const int tb = g * nT;
  STAGE_V(tb * 64)
  STAGE_K(0, (tb + 0) * 64)
  STAGE_K(1, (tb + 1) * 64)

  const int qmax = qb + wq * 32 + 31;

  int cur = 0;
  for (int t = 0; t < nT; t++) {
    const int kt0 = (tb + t) * 64;
    if (t + 1 < nT) { asm volatile("s_waitcnt vmcnt(2)" ::: "memory"); }
    else            { asm volatile("s_waitcnt vmcnt(0)" ::: "memory"); }
    __builtin_amdgcn_s_barrier();

    if (kt0 <= qmax) {
      const u16* Kc = Kg + cur * 4096;
      const u16* Vc = Vg;

      // ---- QK^T ----
      f32x16 s0, s1;
#pragma unroll
      for (int r = 0; r < 16; r++) { s0[r] = 0.f; s1[r] = 0.f; }
      __builtin_amdgcn_s_setprio(1);
#pragma unroll
      for (int ds = 0; ds < 4; ds++) {
        int cs = ((ds * 2 + hi2) ^ x7) * 8;
        bf16x8 kf0 = *(const bf16x8*)(Kc + q32 * 64 + cs);
        bf16x8 kf1 = *(const bf16x8*)(Kc + (32 + q32) * 64 + cs);
        s0 = mfma32(kf0, qf[ds], s0);
        s1 = mfma32(kf1, qf[ds], s1);
      }
      __builtin_amdgcn_s_setprio(0);

      // ---- V fragments from LDS ----
      bf16x8 vf0[4], vf1[4];
#pragma unroll
      for (int ksx = 0; ksx < 4; ksx++) {
        int sc = ((2 * ksx + hi2) ^ x7) * 8;
        vf0[ksx] = *(const bf16x8*)(Vc + q32 * 64 + sc);
        vf1[ksx] = *(const bf16x8*)(Vc + (32 + q32) * 64 + sc);
      }

      // ---- causal mask ----
      if (kt0 + 63 > qb + wq * 32) {
#pragma unroll
        for (int r = 0; r < 16; r++) {
          int kl = (r & 3) + 8 * (r >> 2) + 4 * hi2;
          if (kt0 + kl > qrow) s0[r] = -1e30f;
          if (kt0 + 32 + kl > qrow) s1[r] = -1e30f;
        }
      }

      // ---- lazy max: lane-local trigger, shfl only when tripped ----
      float lpm = -1e30f;
#pragma unroll
      for (int r = 0; r < 16; r++) lpm = fmaxf(lpm, fmaxf(s0[r], s1[r]));
      if (__any(lpm > m_ + 8.f)) {
        float pm = fmaxf(lpm, __shfl_xor(lpm, 32));
        float mn = fmaxf(m_, pm);
        float corr = __builtin_amdgcn_exp2f(m_ - mn);
        m_ = mn;
        l_ *= corr;
#pragma unroll
        for (int r = 0; r < 16; r++) { o0[r] *= corr; o1[r] *= corr; }
      }

      // ---- exp2 + row sum ----
      float rs = 0.f;
#pragma unroll
      for (int r = 0; r < 16; r++) {
        s0[r] = __builtin_amdgcn_exp2f(s0[r] - m_);
        s1[r] = __builtin_amdgcn_exp2f(s1[r] - m_);
        rs += s0[r] + s1[r];
      }
      rs += __shfl_xor(rs, 32);
      l_ += rs;

      // ---- P fragments ----
      bf16x8 pb[4];
#pragma unroll
      for (int ksx = 0; ksx < 4; ksx++) {
        union { uint32_t u[4]; bf16x8 v; } pu;
        if (ksx < 2) {
          int rb = 8 * ksx;
          pu.u[0] = cvtpk(s0[rb + 0], s0[rb + 1]);
          pu.u[1] = cvtpk(s0[rb + 2], s0[rb + 3]);
          pu.u[2] = cvtpk(s0[rb + 4], s0[rb + 5]);
          pu.u[3] = cvtpk(s0[rb + 6], s0[rb + 7]);
        } else {
          int rb = 8 * (ksx - 2);
          pu.u[0] = cvtpk(s1[rb + 0], s1[rb + 1]);
          pu.u[1] = cvtpk(s1[rb + 2], s1[rb + 3]);
          pu.u[2] = cvtpk(s1[rb + 4], s1[rb + 5]);
          pu.u[3] = cvtpk(s1[rb + 6], s1[rb + 7]);
        }
        pb[ksx] = pu.v;
      }

      // ---- PV ----
      __builtin_amdgcn_s_setprio(1);
#pragma unroll
      for (int ksx = 0; ksx < 4; ksx++) {
        o0 = mfma32(vf0[ksx], pb[ksx], o0);
        o1 = mfma32(vf1[ksx], pb[ksx], o1);
      }
      __builtin_amdgcn_s_setprio(0);
    }

    __builtin_amdgcn_s_barrier();  // all waves done reading K[cur] and V
    if (t + 1 < nT) STAGE_V((tb + t + 1) * 64)
    if (t + 2 < nT) STAGE_K(cur, (tb + t + 2) * 64)
    cur ^= 1;
  }

  // ---- merge group 1 into group 0 via LDS scratch (overlays smem) ----
  __syncthreads();
  float* mb = (float*)smem + wq * 2304;
  if (g == 1) {
#pragma unroll
    for (int m = 0; m < 4; m++) {
      f32x4 qa = {o0[4 * m + 0], o0[4 * m + 1], o0[4 * m + 2], o0[4 * m + 3]};
      f32x4 qb2 = {o1[4 * m + 0], o1[4 * m + 1], o1[4 * m + 2], o1[4 * m + 3]};
      *(f32x4*)(mb + m * 256 + (lane << 2)) = qa;
      *(f32x4*)(mb + (4 + m) * 256 + (lane << 2)) = qb2;
    }
    mb[2048 + (lane << 1) + 0] = m_;
    mb[2048 + (lane << 1) + 1] = l_;
  }
  __syncthreads();
  if (g == 0) {
    float m1 = mb[2048 + (lane << 1) + 0];
    float l1 = mb[2048 + (lane << 1) + 1];
    float mm = fmaxf(m_, m1);
    float cA = __builtin_amdgcn_exp2f(m_ - mm);
    float cB = __builtin_amdgcn_exp2f(m1 - mm);
    l_ = l_ * cA + l1 * cB;
#pragma unroll
    for (int m = 0; m < 4; m++) {
      f32x4 qa = *(const f32x4*)(mb + m * 256 + (lane << 2));
      f32x4 qb2 = *(const f32x4*)(mb + (4 + m) * 256 + (lane << 2));
#pragma unroll
      for (int jx = 0; jx < 4; jx++) {
        o0[4 * m + jx] = o0[4 * m + jx] * cA + qa[jx] * cB;
        o1[4 * m + jx] = o1[4 * m + jx] * cA + qb2[jx] * cB;
      }
    }

    const int b = bh >> 4, h = bh & 15;
    float inv = 1.f / l_;
    size_t base = ((size_t)(b * 2048 + qrow)) * 1024 + h * 64;
#pragma unroll
    for (int m = 0; m < 4; m++) {
      uint2 w0, w1;
      w0.x = cvtpk(o0[4 * m + 0] * inv, o0[4 * m + 1] * inv);
      w0.y = cvtpk(o0[4 * m + 2] * inv, o0[4 * m + 3] * inv);
      *(uint2*)(ctx + base + 8 * m + 4 * hi2) = w0;
      w1.x = cvtpk(o1[4 * m + 0] * inv, o1[4 * m + 1] * inv);
      w1.y = cvtpk(o1[4 * m + 2] * inv, o1[4 * m + 3] * inv);
      *(uint2*)(ctx + base + 32 + 8 * m + 4 * hi2) = w1;
    }
  }
}

// ---------------- launch ----------------

extern "C" void kernel_launch(void* const* d_in, const int* in_sizes, int n_in,
                              void* d_out, int out_size, void* d_ws, size_t ws_size,
                              hipStream_t stream) {
  const float* x  = (const float*)d_in[0];
  const float* Wq = (const float*)d_in[1];
  const float* bq = (const float*)d_in[2];
  const float* Wk = (const float*)d_in[3];
  const float* bk = (const float*)d_in[4];
  const float* Wv = (const float*)d_in[5];
  const float* bv = (const float*)d_in[6];
  const float* Wo = (const float*)d_in[7];
  const float* bo = (const float*)d_in[8];

  char* ws = (char*)d_ws;
  u16* xb  = (u16*)(ws);                    // [4096][1024] bf16, 8MB
  u16* wT  = (u16*)(ws + (8u << 20));       // 4 x [1024][1024] bf16, 8MB
  u16* qs  = (u16*)(ws + (16u << 20));      // [32][2048][64] bf16 (pre-scaled)
  u16* ks  = (u16*)(ws + (24u << 20));      // [32][2048][64] bf16
  u16* vts = (u16*)(ws + (32u << 20));      // [32][64][2048] bf16 (k-permuted)
  u16* ctx = (u16*)(ws + (40u << 20));      // [4096][1024] bf16

  x_cvt_kernel<<<4096, 256, 0, stream>>>(x, xb);
  wt_cvt_kernel<<<dim3(16, 16, 4), 256, 0, stream>>>(Wq, Wk, Wv, Wo, wT);
  gemm_qkv_kernel<<<768, 256, 0, stream>>>(xb, wT, bq, bk, bv, qs, ks, vts);
  flash_kernel<<<512, 512, 0, stream>>>(qs, ks, vts, ctx);
  gemm_out_kernel<<<512, 256, 0, stream>>>(ctx, wT + 3 * (1u << 20), bo, (float*)d_out);
}

// Round 22
// 115.346 us; speedup vs baseline: 1.2346x; 1.0229x over previous
//
#include <hip/hip_runtime.h>
#include <stdint.h>

typedef unsigned short u16;
typedef __attribute__((ext_vector_type(8))) __bf16 bf16x8;
typedef __attribute__((ext_vector_type(4))) float f32x4;
typedef __attribute__((ext_vector_type(16))) float f32x16;

__device__ __forceinline__ u16 f2bf(float f) {
  union { float f; uint32_t u; } c; c.f = f;
  uint32_t u = c.u + 0x7fffu + ((c.u >> 16) & 1u);
  return (u16)(u >> 16);
}
__device__ __forceinline__ uint32_t cvtpk(float a, float b) {
  uint32_t r;
  asm("v_cvt_pk_bf16_f32 %0, %1, %2" : "=v"(r) : "v"(a), "v"(b));
  return r;
}

__device__ __forceinline__ void async16(const u16* g, u16* l) {
  __builtin_amdgcn_global_load_lds(
      (const __attribute__((address_space(1))) void*)g,
      (__attribute__((address_space(3))) void*)l, 16, 0, 0);
}

__device__ __forceinline__ f32x4 mfma16(bf16x8 a, bf16x8 b, f32x4 c) {
  return __builtin_amdgcn_mfma_f32_16x16x32_bf16(a, b, c, 0, 0, 0);
}
__device__ __forceinline__ f32x16 mfma32(bf16x8 a, bf16x8 b, f32x16 c) {
  return __builtin_amdgcn_mfma_f32_32x32x16_bf16(a, b, c, 0, 0, 0);
}

// ---------------- conversion kernels ----------------

__global__ __launch_bounds__(256) void x_cvt_kernel(const float* __restrict__ x,
                                                    u16* __restrict__ xb) {
  int i = (blockIdx.x * 256 + threadIdx.x) * 4;
  float4 v = *(const float4*)(x + i);
  uint2 t; t.x = cvtpk(v.x, v.y); t.y = cvtpk(v.z, v.w);
  *(uint2*)(xb + i) = t;
}

// W [K=1024][N=1024] fp32  ->  WT [N][K] bf16
__global__ __launch_bounds__(256) void wt_cvt_kernel(const float* __restrict__ Wq,
                                                     const float* __restrict__ Wk,
                                                     const float* __restrict__ Wv,
                                                     const float* __restrict__ Wo,
                                                     u16* __restrict__ out) {
  __shared__ __align__(16) u16 t[64][72];
  int z = blockIdx.z;
  const float* W = (z == 0) ? Wq : (z == 1) ? Wk : (z == 2) ? Wv : Wo;
  u16* o = out + (size_t)z * (1u << 20);
  int n0 = blockIdx.x * 64, k0 = blockIdx.y * 64;
  int tid = threadIdx.x;
  int c4 = (tid & 15) * 4, r0 = tid >> 4;
#pragma unroll
  for (int i = 0; i < 4; i++) {
    int r = r0 + i * 16;
    float4 v = *(const float4*)(W + (size_t)(k0 + r) * 1024 + n0 + c4);
    t[c4 + 0][r] = f2bf(v.x);
    t[c4 + 1][r] = f2bf(v.y);
    t[c4 + 2][r] = f2bf(v.z);
    t[c4 + 3][r] = f2bf(v.w);
  }
  __syncthreads();
  int n = tid >> 2, kc = (tid & 3) * 16;
  uint4 a = *(const uint4*)&t[n][kc];
  uint4 b = *(const uint4*)&t[n][kc + 8];
  *(uint4*)(o + (size_t)(n0 + n) * 1024 + k0 + kc) = a;
  *(uint4*)(o + (size_t)(n0 + n) * 1024 + k0 + kc + 8) = b;
}

// ------------- GEMM core v4: DEPTH-3 counted-vmcnt pipeline ----------------
template <int TN>
__device__ __forceinline__ void gemm_core3(const u16* __restrict__ A,
                                           const u16* __restrict__ Bt,
                                           u16* As, u16* Bs,
                                           f32x4 (&acc)[4][TN / 32],
                                           int m0, int n0) {
  constexpr int NJ = TN / 32;
  constexpr int ASZ = 128 * 32, BSZ = TN * 32;
  const int tid = threadIdx.x, wave = tid >> 6, lane = tid & 63;
  const int low = lane & 15, hi = lane >> 4;
  const int wm = wave >> 1, wn = wave & 1;
  const f32x4 fzero = {0.f, 0.f, 0.f, 0.f};
#pragma unroll
  for (int i = 0; i < 4; i++)
#pragma unroll
    for (int j = 0; j < NJ; j++) acc[i][j] = fzero;

  const int ea0 = wave * 128 + lane, ea1 = ea0 + 64;
  const u16* ga0 = A + (size_t)(m0 + (ea0 >> 2)) * 1024 + (ea0 & 3) * 8;
  const u16* ga1 = A + (size_t)(m0 + (ea1 >> 2)) * 1024 + (ea1 & 3) * 8;
  u16* la0 = As + (wave * 2 + 0) * 512;
  u16* la1 = As + (wave * 2 + 1) * 512;

  const int eb0 = (TN == 128) ? (wave * 128 + lane) : (wave * 64 + lane);
  const int eb1 = eb0 + 64;
  const u16* gb0 = Bt + (size_t)(n0 + (eb0 >> 2)) * 1024 + (eb0 & 3) * 8;
  const u16* gb1 = Bt + (size_t)(n0 + (eb1 >> 2)) * 1024 + (eb1 & 3) * 8;
  u16* lb0 = Bs + ((TN == 128) ? (wave * 2 + 0) * 512 : wave * 512);
  u16* lb1 = Bs + (wave * 2 + 1) * 512;

  const u16* ap = As + (wm * 64 + low) * 32 + hi * 8;
  const u16* bp = Bs + (wn * (TN / 2) + low) * 32 + hi * 8;

#define GSTAGE(buf, KT)                                                        \
  {                                                                            \
    async16(ga0 + (KT), la0 + (buf) * ASZ);                                    \
    async16(ga1 + (KT), la1 + (buf) * ASZ);                                    \
    async16(gb0 + (KT), lb0 + (buf) * BSZ);                                    \
    if (TN == 128) async16(gb1 + (KT), lb1 + (buf) * BSZ);                     \
  }

  GSTAGE(0, 0)
  GSTAGE(1, 32)
  GSTAGE(2, 64)
  int buf = 0;
  for (int kt = 0; kt < 1024; kt += 32) {
    if (kt + 96 <= 1024) {
      if constexpr (TN == 128) asm volatile("s_waitcnt vmcnt(8)" ::: "memory");
      else                     asm volatile("s_waitcnt vmcnt(6)" ::: "memory");
    } else if (kt + 64 <= 1024) {
      if constexpr (TN == 128) asm volatile("s_waitcnt vmcnt(4)" ::: "memory");
      else                     asm volatile("s_waitcnt vmcnt(3)" ::: "memory");
    } else {
      asm volatile("s_waitcnt vmcnt(0)" ::: "memory");
    }
    __builtin_amdgcn_s_barrier();

    bf16x8 af[4], bfv[NJ];
#pragma unroll
    for (int i = 0; i < 4; i++)
      af[i] = *(const bf16x8*)(ap + buf * ASZ + i * 16 * 32);
#pragma unroll
    for (int j = 0; j < NJ; j++)
      bfv[j] = *(const bf16x8*)(bp + buf * BSZ + j * 16 * 32);
#pragma unroll
    for (int i = 0; i < 4; i++)
#pragma unroll
      for (int j = 0; j < NJ; j++) acc[i][j] = mfma16(af[i], bfv[j], acc[i][j]);

    __builtin_amdgcn_s_barrier();
    if (kt + 96 < 1024) GSTAGE(buf, kt + 96)
    buf = (buf == 2) ? 0 : buf + 1;
  }
#undef GSTAGE
}

// QKV projection, XCD-chunked flat grid of 768 blocks.
__global__ __launch_bounds__(256) void gemm_qkv_kernel(
    const u16* __restrict__ xb, const u16* __restrict__ wT,
    const float* __restrict__ bq, const float* __restrict__ bk,
    const float* __restrict__ bv,
    u16* __restrict__ qs, u16* __restrict__ ks, u16* __restrict__ vts) {
  __shared__ __align__(16) u16 smem[24576];
  u16* As = smem;
  u16* Bs = smem + 12288;

  const int bid = blockIdx.x;
  const int c = bid & 7;
  const int j = bid >> 3;
  const int z = j >> 5;
  const int jj = j & 31;
  const int ytile = (c >> 1) * 8 + (jj >> 2);
  const int xtile = (c & 1) * 4 + (jj & 3);
  const int m0 = ytile * 128, n0 = xtile * 128;

  const u16* Bt = wT + (size_t)z * (1u << 20);
  f32x4 acc[4][4];
  gemm_core3<128>(xb, Bt, As, Bs, acc, m0, n0);

  const float* bias = (z == 0) ? bq : (z == 1) ? bk : bv;
  u16* out = (z == 0) ? qs : (z == 1) ? ks : vts;
  const float scale = (z == 0) ? 0.180336880f : 1.0f;
  const int tid = threadIdx.x, wave = tid >> 6, lane = tid & 63;
  const int low = lane & 15, hi = lane >> 4;
  const int wm = wave >> 1, wn = wave & 1;

  const int h = (n0 >> 6) + wn;
  const int gmb = m0 + wm * 64;
  const int b = gmb >> 11;
  const int lb = gmb & 2047;

  u16* tile = smem + wave * 4360;
#pragma unroll
  for (int i = 0; i < 4; i++)
#pragma unroll
    for (int jx = 0; jx < 4; jx++) {
      int hd = jx * 16 + low;
      float bval = bias[h * 64 + hd];
#pragma unroll
      for (int r = 0; r < 4; r++) {
        int row = i * 16 + hi * 4 + r;
        tile[row * 68 + hd] = f2bf((acc[i][jx][r] + bval) * scale);
      }
    }

  if (z != 2) {
    u16* dst = out + ((size_t)((b * 16 + h) * 2048 + lb + lane)) * 64;
    const u16* src = tile + lane * 68;
#pragma unroll
    for (int cc = 0; cc < 4; cc++) {
      uint2 a0 = *(const uint2*)(src + cc * 16 + 0);
      uint2 a1 = *(const uint2*)(src + cc * 16 + 4);
      uint2 a2 = *(const uint2*)(src + cc * 16 + 8);
      uint2 a3 = *(const uint2*)(src + cc * 16 + 12);
      uint4 w0; w0.x = a0.x; w0.y = a0.y; w0.z = a1.x; w0.w = a1.y;
      uint4 w1; w1.x = a2.x; w1.y = a2.y; w1.z = a3.x; w1.w = a3.y;
      *(uint4*)(dst + cc * 16 + 0) = w0;
      *(uint4*)(dst + cc * 16 + 8) = w1;
    }
  } else {
    int l4 = (lane & 15) * 4;
    int lp4 = (l4 & ~12) | ((l4 & 4) << 1) | ((l4 & 8) >> 1);
    int ghd = lane >> 4;
    u16* vbase = out + ((size_t)(b * 16 + h) * 64) * 2048 + lb + lp4;
#pragma unroll
    for (int s = 0; s < 16; s++) {
      int hd = s * 4 + ghd;
      uint32_t v0 = tile[(l4 + 0) * 68 + hd];
      uint32_t v1 = tile[(l4 + 1) * 68 + hd];
      uint32_t v2 = tile[(l4 + 2) * 68 + hd];
      uint32_t v3 = tile[(l4 + 3) * 68 + hd];
      uint2 w; w.x = v0 | (v1 << 16); w.y = v2 | (v3 << 16);
      *(uint2*)(vbase + (size_t)hd * 2048) = w;
    }
  }
}

// output projection: XCD-chunked flat grid of 512 blocks (128x64 tiles)
__global__ __launch_bounds__(256) void gemm_out_kernel(
    const u16* __restrict__ ctx, const u16* __restrict__ woT,
    const float* __restrict__ bo, float* __restrict__ out) {
  __shared__ __align__(16) u16 As[3 * 128 * 32];
  __shared__ __align__(16) u16 Bs[3 * 64 * 32];

  const int bid = blockIdx.x;
  const int c = bid & 7;
  const int j = bid >> 3;
  const int ytile = (c >> 1) * 8 + (j >> 3);
  const int xtile = (c & 1) * 8 + (j & 7);
  const int m0 = ytile * 128, n0 = xtile * 64;

  f32x4 acc[4][2];
  gemm_core3<64>(ctx, woT, As, Bs, acc, m0, n0);
  const int tid = threadIdx.x, wave = tid >> 6, lane = tid & 63;
  const int low = lane & 15, hi = lane >> 4;
  const int wm = wave >> 1, wn = wave & 1;
#pragma unroll
  for (int i = 0; i < 4; i++)
#pragma unroll
    for (int jx = 0; jx < 2; jx++) {
      int gn = n0 + wn * 32 + jx * 16 + low;
      float bval = bo[gn];
#pragma unroll
      for (int r = 0; r < 4; r++) {
        int gm = m0 + wm * 64 + i * 16 + hi * 4 + r;
        out[(size_t)gm * 1024 + gn] = acc[i][jx][r] + bval;
      }
    }
}

// ---------------- flash attention v18: ONE barrier per tile ----------------
// r19's proven v15 kernel (47.7us) with the loop re-ordered to the
// stage-before-compute pattern (proven race-free in the r16 GEMM core):
// per tile: wait vmcnt(0) [own stage(t) loads] -> barrier [all waves'
// loads visible; also: all waves finished t-1's compute = last readers of
// buffer cur^1] -> STAGE(cur^1, t+1) -> compute(cur). Removes the second
// per-tile barrier. Prefetch cover = one full compute phase (~2K cyc) vs
// K/V L2-hit latency (~300 cyc). Deferred lacc row-sum + lazy max as r19.
__global__ __launch_bounds__(512) void flash_kernel(
    const u16* __restrict__ Qs, const u16* __restrict__ Ks,
    const u16* __restrict__ Vts, u16* __restrict__ ctx) {
  __shared__ __align__(16) u16 Kls[2][2][64 * 64];
  __shared__ __align__(16) u16 Vls[2][2][64 * 64];

  const int bid = blockIdx.x;
  const int qt = (bid < 256) ? (15 - (bid >> 5)) : ((bid - 256) >> 5);
  const int bh = bid & 31;
  const int qb = qt * 128;
  const int nT = qt + 1;

  const int tid = threadIdx.x, wave = tid >> 6, lane = tid & 63;
  const int wq = wave & 3, g = wave >> 2;
  const int q32 = lane & 31, hi2 = lane >> 5;
  const int x7 = q32 & 7;

  const u16* Qb = Qs + (size_t)bh * (2048 * 64);
  const u16* Kb = Ks + (size_t)bh * (2048 * 64);
  const u16* Vb = Vts + (size_t)bh * (64 * 2048);

  const int qrow = qb + wq * 32 + q32;
  bf16x8 qf[4];
#pragma unroll
  for (int ds = 0; ds < 4; ds++)
    qf[ds] = *(const bf16x8*)(Qb + (size_t)qrow * 64 + ds * 16 + hi2 * 8);

  f32x16 o0, o1, lacc;
#pragma unroll
  for (int r = 0; r < 16; r++) { o0[r] = 0.f; o1[r] = 0.f; lacc[r] = 0.f; }
  float m_ = -1e30f;

#define STAGE(buf, KT0)                                                        \
  {                                                                            \
    _Pragma("unroll") for (int i = 0; i < 2; i++) {                            \
      int row = (wq * 2 + i) * 8 + (lane >> 3);                                \
      async16(Kb + (size_t)((KT0) + row) * 64 +                                \
                  (((lane & 7) ^ (row & 7)) * 8),                              \
              &Kls[g][buf][(wq * 2 + i) * 512]);                               \
      async16(Vb + (size_t)row * 2048 + (KT0) +                                \
                  (((lane & 7) ^ (row & 7)) * 8),                              \
              &Vls[g][buf][(wq * 2 + i) * 512]);                               \
    }                                                                          \
  }

  const int tb = g * nT;
  STAGE(0, (tb + 0) * 64)

  const int qmax = qb + wq * 32 + 31;

  int cur = 0;
  for (int t = 0; t < nT; t++) {
    const int kt0 = (tb + t) * 64;
    asm volatile("s_waitcnt vmcnt(0)" ::: "memory");
    __builtin_amdgcn_s_barrier();
    if (t + 1 < nT) STAGE(cur ^ 1, (tb + t + 1) * 64)

    if (kt0 <= qmax) {
      const u16* Kc = &Kls[g][cur][0];
      const u16* Vc = &Vls[g][cur][0];

      // ---- QK^T ----
      f32x16 s0, s1;
#pragma unroll
      for (int r = 0; r < 16; r++) { s0[r] = 0.f; s1[r] = 0.f; }
      __builtin_amdgcn_s_setprio(1);
#pragma unroll
      for (int ds = 0; ds < 4; ds++) {
        int cs = ((ds * 2 + hi2) ^ x7) * 8;
        bf16x8 kf0 = *(const bf16x8*)(Kc + q32 * 64 + cs);
        bf16x8 kf1 = *(const bf16x8*)(Kc + (32 + q32) * 64 + cs);
        s0 = mfma32(kf0, qf[ds], s0);
        s1 = mfma32(kf1, qf[ds], s1);
      }
      __builtin_amdgcn_s_setprio(0);

      // ---- V fragments ----
      bf16x8 vf0[4], vf1[4];
#pragma unroll
      for (int ksx = 0; ksx < 4; ksx++) {
        int sc = ((2 * ksx + hi2) ^ x7) * 8;
        vf0[ksx] = *(const bf16x8*)(Vc + q32 * 64 + sc);
        vf1[ksx] = *(const bf16x8*)(Vc + (32 + q32) * 64 + sc);
      }

      // ---- causal mask ----
      if (kt0 + 63 > qb + wq * 32) {
#pragma unroll
        for (int r = 0; r < 16; r++) {
          int kl = (r & 3) + 8 * (r >> 2) + 4 * hi2;
          if (kt0 + kl > qrow) s0[r] = -1e30f;
          if (kt0 + 32 + kl > qrow) s1[r] = -1e30f;
        }
      }

      // ---- lazy max: lane-local trigger, shfl only when tripped ----
      float lpm = -1e30f;
#pragma unroll
      for (int r = 0; r < 16; r++) lpm = fmaxf(lpm, fmaxf(s0[r], s1[r]));
      if (__any(lpm > m_ + 8.f)) {
        float pm = fmaxf(lpm, __shfl_xor(lpm, 32));
        float mn = fmaxf(m_, pm);
        float corr = __builtin_amdgcn_exp2f(m_ - mn);
        m_ = mn;
#pragma unroll
        for (int r = 0; r < 16; r++) {
          o0[r] *= corr; o1[r] *= corr; lacc[r] *= corr;
        }
      }

      // ---- exp2 + deferred row-sum ----
#pragma unroll
      for (int r = 0; r < 16; r++) {
        s0[r] = __builtin_amdgcn_exp2f(s0[r] - m_);
        s1[r] = __builtin_amdgcn_exp2f(s1[r] - m_);
        lacc[r] += s0[r] + s1[r];
      }

      // ---- P fragments ----
      bf16x8 pb[4];
#pragma unroll
      for (int ksx = 0; ksx < 4; ksx++) {
        union { uint32_t u[4]; bf16x8 v; } pu;
        if (ksx < 2) {
          int rb = 8 * ksx;
          pu.u[0] = cvtpk(s0[rb + 0], s0[rb + 1]);
          pu.u[1] = cvtpk(s0[rb + 2], s0[rb + 3]);
          pu.u[2] = cvtpk(s0[rb + 4], s0[rb + 5]);
          pu.u[3] = cvtpk(s0[rb + 6], s0[rb + 7]);
        } else {
          int rb = 8 * (ksx - 2);
          pu.u[0] = cvtpk(s1[rb + 0], s1[rb + 1]);
          pu.u[1] = cvtpk(s1[rb + 2], s1[rb + 3]);
          pu.u[2] = cvtpk(s1[rb + 4], s1[rb + 5]);
          pu.u[3] = cvtpk(s1[rb + 6], s1[rb + 7]);
        }
        pb[ksx] = pu.v;
      }

      // ---- PV ----
      __builtin_amdgcn_s_setprio(1);
#pragma unroll
      for (int ksx = 0; ksx < 4; ksx++) {
        o0 = mfma32(vf0[ksx], pb[ksx], o0);
        o1 = mfma32(vf1[ksx], pb[ksx], o1);
      }
      __builtin_amdgcn_s_setprio(0);
    }

    cur ^= 1;
  }

  // ---- finalize l: one tree + one shfl per kernel ----
  float l_ = 0.f;
#pragma unroll
  for (int r = 0; r < 16; r++) l_ += lacc[r];
  l_ += __shfl_xor(l_, 32);

  // ---- merge group 1 into group 0 via LDS scratch at Kls base ----
  __syncthreads();
  float* mb = (float*)&Kls[0][0][0] + wq * 2304;
  if (g == 1) {
#pragma unroll
    for (int m = 0; m < 4; m++) {
      f32x4 qa = {o0[4 * m + 0], o0[4 * m + 1], o0[4 * m + 2], o0[4 * m + 3]};
      f32x4 qb2 = {o1[4 * m + 0], o1[4 * m + 1], o1[4 * m + 2], o1[4 * m + 3]};
      *(f32x4*)(mb + m * 256 + (lane << 2)) = qa;
      *(f32x4*)(mb + (4 + m) * 256 + (lane << 2)) = qb2;
    }
    mb[2048 + (lane << 1) + 0] = m_;
    mb[2048 + (lane << 1) + 1] = l_;
  }
  __syncthreads();
  if (g == 0) {
    float m1 = mb[2048 + (lane << 1) + 0];
    float l1 = mb[2048 + (lane << 1) + 1];
    float mm = fmaxf(m_, m1);
    float cA = __builtin_amdgcn_exp2f(m_ - mm);
    float cB = __builtin_amdgcn_exp2f(m1 - mm);
    l_ = l_ * cA + l1 * cB;
#pragma unroll
    for (int m = 0; m < 4; m++) {
      f32x4 qa = *(const f32x4*)(mb + m * 256 + (lane << 2));
      f32x4 qb2 = *(const f32x4*)(mb + (4 + m) * 256 + (lane << 2));
#pragma unroll
      for (int jx = 0; jx < 4; jx++) {
        o0[4 * m + jx] = o0[4 * m + jx] * cA + qa[jx] * cB;
        o1[4 * m + jx] = o1[4 * m + jx] * cA + qb2[jx] * cB;
      }
    }

    const int b = bh >> 4, h = bh & 15;
    float inv = 1.f / l_;
    size_t base = ((size_t)(b * 2048 + qrow)) * 1024 + h * 64;
#pragma unroll
    for (int m = 0; m < 4; m++) {
      uint2 w0, w1;
      w0.x = cvtpk(o0[4 * m + 0] * inv, o0[4 * m + 1] * inv);
      w0.y = cvtpk(o0[4 * m + 2] * inv, o0[4 * m + 3] * inv);
      *(uint2*)(ctx + base + 8 * m + 4 * hi2) = w0;
      w1.x = cvtpk(o1[4 * m + 0] * inv, o1[4 * m + 1] * inv);
      w1.y = cvtpk(o1[4 * m + 2] * inv, o1[4 * m + 3] * inv);
      *(uint2*)(ctx + base + 32 + 8 * m + 4 * hi2) = w1;
    }
  }
}

// ---------------- launch ----------------

extern "C" void kernel_launch(void* const* d_in, const int* in_sizes, int n_in,
                              void* d_out, int out_size, void* d_ws, size_t ws_size,
                              hipStream_t stream) {
  const float* x  = (const float*)d_in[0];
  const float* Wq = (const float*)d_in[1];
  const float* bq = (const float*)d_in[2];
  const float* Wk = (const float*)d_in[3];
  const float* bk = (const float*)d_in[4];
  const float* Wv = (const float*)d_in[5];
  const float* bv = (const float*)d_in[6];
  const float* Wo = (const float*)d_in[7];
  const float* bo = (const float*)d_in[8];

  char* ws = (char*)d_ws;
  u16* xb  = (u16*)(ws);                    // [4096][1024] bf16, 8MB
  u16* wT  = (u16*)(ws + (8u << 20));       // 4 x [1024][1024] bf16, 8MB
  u16* qs  = (u16*)(ws + (16u << 20));      // [32][2048][64] bf16 (pre-scaled)
  u16* ks  = (u16*)(ws + (24u << 20));      // [32][2048][64] bf16
  u16* vts = (u16*)(ws + (32u << 20));      // [32][64][2048] bf16 (k-permuted)
  u16* ctx = (u16*)(ws + (40u << 20));      // [4096][1024] bf16

  x_cvt_kernel<<<4096, 256, 0, stream>>>(x, xb);
  wt_cvt_kernel<<<dim3(16, 16, 4), 256, 0, stream>>>(Wq, Wk, Wv, Wo, wT);
  gemm_qkv_kernel<<<768, 256, 0, stream>>>(xb, wT, bq, bk, bv, qs, ks, vts);
  flash_kernel<<<512, 512, 0, stream>>>(qs, ks, vts, ctx);
  gemm_out_kernel<<<512, 256, 0, stream>>>(ctx, wT + 3 * (1u << 20), bo, (float*)d_out);
}

// Round 23
// 113.196 us; speedup vs baseline: 1.2580x; 1.0190x over previous
//
#include <hip/hip_runtime.h>
#include <stdint.h>

typedef unsigned short u16;
typedef __attribute__((ext_vector_type(8))) __bf16 bf16x8;
typedef __attribute__((ext_vector_type(4))) float f32x4;
typedef __attribute__((ext_vector_type(16))) float f32x16;

__device__ __forceinline__ u16 f2bf(float f) {
  union { float f; uint32_t u; } c; c.f = f;
  uint32_t u = c.u + 0x7fffu + ((c.u >> 16) & 1u);
  return (u16)(u >> 16);
}
__device__ __forceinline__ uint32_t cvtpk(float a, float b) {
  uint32_t r;
  asm("v_cvt_pk_bf16_f32 %0, %1, %2" : "=v"(r) : "v"(a), "v"(b));
  return r;
}

__device__ __forceinline__ void async16(const u16* g, u16* l) {
  __builtin_amdgcn_global_load_lds(
      (const __attribute__((address_space(1))) void*)g,
      (__attribute__((address_space(3))) void*)l, 16, 0, 0);
}

__device__ __forceinline__ f32x4 mfma16(bf16x8 a, bf16x8 b, f32x4 c) {
  return __builtin_amdgcn_mfma_f32_16x16x32_bf16(a, b, c, 0, 0, 0);
}
__device__ __forceinline__ f32x16 mfma32(bf16x8 a, bf16x8 b, f32x16 c) {
  return __builtin_amdgcn_mfma_f32_32x32x16_bf16(a, b, c, 0, 0, 0);
}

// ---------------- fused conversion kernel ----------------
// bid < 4096: x fp32 -> xb bf16 (1024 elems/block).
// bid >= 4096: W transpose+convert; rem=(bid-4096): z=rem>>8,
// idx=rem&255: n0=(idx&15)*64, k0=(idx>>4)*64.
__global__ __launch_bounds__(256) void cvt_kernel(
    const float* __restrict__ x, u16* __restrict__ xb,
    const float* __restrict__ Wq, const float* __restrict__ Wk,
    const float* __restrict__ Wv, const float* __restrict__ Wo,
    u16* __restrict__ wT) {
  __shared__ __align__(16) u16 t[64][72];
  const int bid = blockIdx.x;
  const int tid = threadIdx.x;
  if (bid < 4096) {
    int i = (bid * 256 + tid) * 4;
    float4 v = *(const float4*)(x + i);
    uint2 o; o.x = cvtpk(v.x, v.y); o.y = cvtpk(v.z, v.w);
    *(uint2*)(xb + i) = o;
    return;
  }
  const int rem = bid - 4096;
  const int z = rem >> 8;
  const int idx = rem & 255;
  const int n0 = (idx & 15) * 64, k0 = (idx >> 4) * 64;
  const float* W = (z == 0) ? Wq : (z == 1) ? Wk : (z == 2) ? Wv : Wo;
  u16* o = wT + (size_t)z * (1u << 20);
  int c4 = (tid & 15) * 4, r0 = tid >> 4;
#pragma unroll
  for (int i = 0; i < 4; i++) {
    int r = r0 + i * 16;
    float4 v = *(const float4*)(W + (size_t)(k0 + r) * 1024 + n0 + c4);
    t[c4 + 0][r] = f2bf(v.x);
    t[c4 + 1][r] = f2bf(v.y);
    t[c4 + 2][r] = f2bf(v.z);
    t[c4 + 3][r] = f2bf(v.w);
  }
  __syncthreads();
  int n = tid >> 2, kc = (tid & 3) * 16;
  uint4 a = *(const uint4*)&t[n][kc];
  uint4 b = *(const uint4*)&t[n][kc + 8];
  *(uint4*)(o + (size_t)(n0 + n) * 1024 + k0 + kc) = a;
  *(uint4*)(o + (size_t)(n0 + n) * 1024 + k0 + kc + 8) = b;
}

// ------------- GEMM core v4: DEPTH-3 counted-vmcnt pipeline ----------------
template <int TN>
__device__ __forceinline__ void gemm_core3(const u16* __restrict__ A,
                                           const u16* __restrict__ Bt,
                                           u16* As, u16* Bs,
                                           f32x4 (&acc)[4][TN / 32],
                                           int m0, int n0) {
  constexpr int NJ = TN / 32;
  constexpr int ASZ = 128 * 32, BSZ = TN * 32;
  const int tid = threadIdx.x, wave = tid >> 6, lane = tid & 63;
  const int low = lane & 15, hi = lane >> 4;
  const int wm = wave >> 1, wn = wave & 1;
  const f32x4 fzero = {0.f, 0.f, 0.f, 0.f};
#pragma unroll
  for (int i = 0; i < 4; i++)
#pragma unroll
    for (int j = 0; j < NJ; j++) acc[i][j] = fzero;

  const int ea0 = wave * 128 + lane, ea1 = ea0 + 64;
  const u16* ga0 = A + (size_t)(m0 + (ea0 >> 2)) * 1024 + (ea0 & 3) * 8;
  const u16* ga1 = A + (size_t)(m0 + (ea1 >> 2)) * 1024 + (ea1 & 3) * 8;
  u16* la0 = As + (wave * 2 + 0) * 512;
  u16* la1 = As + (wave * 2 + 1) * 512;

  const int eb0 = (TN == 128) ? (wave * 128 + lane) : (wave * 64 + lane);
  const int eb1 = eb0 + 64;
  const u16* gb0 = Bt + (size_t)(n0 + (eb0 >> 2)) * 1024 + (eb0 & 3) * 8;
  const u16* gb1 = Bt + (size_t)(n0 + (eb1 >> 2)) * 1024 + (eb1 & 3) * 8;
  u16* lb0 = Bs + ((TN == 128) ? (wave * 2 + 0) * 512 : wave * 512);
  u16* lb1 = Bs + (wave * 2 + 1) * 512;

  const u16* ap = As + (wm * 64 + low) * 32 + hi * 8;
  const u16* bp = Bs + (wn * (TN / 2) + low) * 32 + hi * 8;

#define GSTAGE(buf, KT)                                                        \
  {                                                                            \
    async16(ga0 + (KT), la0 + (buf) * ASZ);                                    \
    async16(ga1 + (KT), la1 + (buf) * ASZ);                                    \
    async16(gb0 + (KT), lb0 + (buf) * BSZ);                                    \
    if (TN == 128) async16(gb1 + (KT), lb1 + (buf) * BSZ);                     \
  }

  GSTAGE(0, 0)
  GSTAGE(1, 32)
  GSTAGE(2, 64)
  int buf = 0;
  for (int kt = 0; kt < 1024; kt += 32) {
    if (kt + 96 <= 1024) {
      if constexpr (TN == 128) asm volatile("s_waitcnt vmcnt(8)" ::: "memory");
      else                     asm volatile("s_waitcnt vmcnt(6)" ::: "memory");
    } else if (kt + 64 <= 1024) {
      if constexpr (TN == 128) asm volatile("s_waitcnt vmcnt(4)" ::: "memory");
      else                     asm volatile("s_waitcnt vmcnt(3)" ::: "memory");
    } else {
      asm volatile("s_waitcnt vmcnt(0)" ::: "memory");
    }
    __builtin_amdgcn_s_barrier();

    bf16x8 af[4], bfv[NJ];
#pragma unroll
    for (int i = 0; i < 4; i++)
      af[i] = *(const bf16x8*)(ap + buf * ASZ + i * 16 * 32);
#pragma unroll
    for (int j = 0; j < NJ; j++)
      bfv[j] = *(const bf16x8*)(bp + buf * BSZ + j * 16 * 32);
#pragma unroll
    for (int i = 0; i < 4; i++)
#pragma unroll
      for (int j = 0; j < NJ; j++) acc[i][j] = mfma16(af[i], bfv[j], acc[i][j]);

    __builtin_amdgcn_s_barrier();
    if (kt + 96 < 1024) GSTAGE(buf, kt + 96)
    buf = (buf == 2) ? 0 : buf + 1;
  }
#undef GSTAGE
}

// QKV projection, XCD-chunked flat grid of 768 blocks.
__global__ __launch_bounds__(256) void gemm_qkv_kernel(
    const u16* __restrict__ xb, const u16* __restrict__ wT,
    const float* __restrict__ bq, const float* __restrict__ bk,
    const float* __restrict__ bv,
    u16* __restrict__ qs, u16* __restrict__ ks, u16* __restrict__ vts) {
  __shared__ __align__(16) u16 smem[24576];
  u16* As = smem;
  u16* Bs = smem + 12288;

  const int bid = blockIdx.x;
  const int c = bid & 7;
  const int j = bid >> 3;
  const int z = j >> 5;
  const int jj = j & 31;
  const int ytile = (c >> 1) * 8 + (jj >> 2);
  const int xtile = (c & 1) * 4 + (jj & 3);
  const int m0 = ytile * 128, n0 = xtile * 128;

  const u16* Bt = wT + (size_t)z * (1u << 20);
  f32x4 acc[4][4];
  gemm_core3<128>(xb, Bt, As, Bs, acc, m0, n0);

  const float* bias = (z == 0) ? bq : (z == 1) ? bk : bv;
  u16* out = (z == 0) ? qs : (z == 1) ? ks : vts;
  const float scale = (z == 0) ? 0.180336880f : 1.0f;
  const int tid = threadIdx.x, wave = tid >> 6, lane = tid & 63;
  const int low = lane & 15, hi = lane >> 4;
  const int wm = wave >> 1, wn = wave & 1;

  const int h = (n0 >> 6) + wn;
  const int gmb = m0 + wm * 64;
  const int b = gmb >> 11;
  const int lb = gmb & 2047;

  u16* tile = smem + wave * 4360;
#pragma unroll
  for (int i = 0; i < 4; i++)
#pragma unroll
    for (int jx = 0; jx < 4; jx++) {
      int hd = jx * 16 + low;
      float bval = bias[h * 64 + hd];
#pragma unroll
      for (int r = 0; r < 4; r++) {
        int row = i * 16 + hi * 4 + r;
        tile[row * 68 + hd] = f2bf((acc[i][jx][r] + bval) * scale);
      }
    }

  if (z != 2) {
    u16* dst = out + ((size_t)((b * 16 + h) * 2048 + lb + lane)) * 64;
    const u16* src = tile + lane * 68;
#pragma unroll
    for (int cc = 0; cc < 4; cc++) {
      uint2 a0 = *(const uint2*)(src + cc * 16 + 0);
      uint2 a1 = *(const uint2*)(src + cc * 16 + 4);
      uint2 a2 = *(const uint2*)(src + cc * 16 + 8);
      uint2 a3 = *(const uint2*)(src + cc * 16 + 12);
      uint4 w0; w0.x = a0.x; w0.y = a0.y; w0.z = a1.x; w0.w = a1.y;
      uint4 w1; w1.x = a2.x; w1.y = a2.y; w1.z = a3.x; w1.w = a3.y;
      *(uint4*)(dst + cc * 16 + 0) = w0;
      *(uint4*)(dst + cc * 16 + 8) = w1;
    }
  } else {
    int l4 = (lane & 15) * 4;
    int lp4 = (l4 & ~12) | ((l4 & 4) << 1) | ((l4 & 8) >> 1);
    int ghd = lane >> 4;
    u16* vbase = out + ((size_t)(b * 16 + h) * 64) * 2048 + lb + lp4;
#pragma unroll
    for (int s = 0; s < 16; s++) {
      int hd = s * 4 + ghd;
      uint32_t v0 = tile[(l4 + 0) * 68 + hd];
      uint32_t v1 = tile[(l4 + 1) * 68 + hd];
      uint32_t v2 = tile[(l4 + 2) * 68 + hd];
      uint32_t v3 = tile[(l4 + 3) * 68 + hd];
      uint2 w; w.x = v0 | (v1 << 16); w.y = v2 | (v3 << 16);
      *(uint2*)(vbase + (size_t)hd * 2048) = w;
    }
  }
}

// output projection: XCD-chunked flat grid of 512 blocks (128x64 tiles)
__global__ __launch_bounds__(256) void gemm_out_kernel(
    const u16* __restrict__ ctx, const u16* __restrict__ woT,
    const float* __restrict__ bo, float* __restrict__ out) {
  __shared__ __align__(16) u16 As[3 * 128 * 32];
  __shared__ __align__(16) u16 Bs[3 * 64 * 32];

  const int bid = blockIdx.x;
  const int c = bid & 7;
  const int j = bid >> 3;
  const int ytile = (c >> 1) * 8 + (j >> 3);
  const int xtile = (c & 1) * 8 + (j & 7);
  const int m0 = ytile * 128, n0 = xtile * 64;

  f32x4 acc[4][2];
  gemm_core3<64>(ctx, woT, As, Bs, acc, m0, n0);
  const int tid = threadIdx.x, wave = tid >> 6, lane = tid & 63;
  const int low = lane & 15, hi = lane >> 4;
  const int wm = wave >> 1, wn = wave & 1;
#pragma unroll
  for (int i = 0; i < 4; i++)
#pragma unroll
    for (int jx = 0; jx < 2; jx++) {
      int gn = n0 + wn * 32 + jx * 16 + low;
      float bval = bo[gn];
#pragma unroll
      for (int r = 0; r < 4; r++) {
        int gm = m0 + wm * 64 + i * 16 + hi * 4 + r;
        out[(size_t)gm * 1024 + gn] = acc[i][jx][r] + bval;
      }
    }
}

// ---------------- flash attention (r19-exact, best measured 47.7us) -------
// 512 blocks x 512 threads, KV-split groups, double-buffer, counted
// vmcnt(4), two barriers/tile. Deferred lacc row-sum + lazy max.
__global__ __launch_bounds__(512) void flash_kernel(
    const u16* __restrict__ Qs, const u16* __restrict__ Ks,
    const u16* __restrict__ Vts, u16* __restrict__ ctx) {
  __shared__ __align__(16) u16 Kls[2][2][64 * 64];
  __shared__ __align__(16) u16 Vls[2][2][64 * 64];

  const int bid = blockIdx.x;
  const int qt = (bid < 256) ? (15 - (bid >> 5)) : ((bid - 256) >> 5);
  const int bh = bid & 31;
  const int qb = qt * 128;
  const int nT = qt + 1;

  const int tid = threadIdx.x, wave = tid >> 6, lane = tid & 63;
  const int wq = wave & 3, g = wave >> 2;
  const int q32 = lane & 31, hi2 = lane >> 5;
  const int x7 = q32 & 7;

  const u16* Qb = Qs + (size_t)bh * (2048 * 64);
  const u16* Kb = Ks + (size_t)bh * (2048 * 64);
  const u16* Vb = Vts + (size_t)bh * (64 * 2048);

  const int qrow = qb + wq * 32 + q32;
  bf16x8 qf[4];
#pragma unroll
  for (int ds = 0; ds < 4; ds++)
    qf[ds] = *(const bf16x8*)(Qb + (size_t)qrow * 64 + ds * 16 + hi2 * 8);

  f32x16 o0, o1, lacc;
#pragma unroll
  for (int r = 0; r < 16; r++) { o0[r] = 0.f; o1[r] = 0.f; lacc[r] = 0.f; }
  float m_ = -1e30f;

#define STAGE(buf, KT0)                                                        \
  {                                                                            \
    _Pragma("unroll") for (int i = 0; i < 2; i++) {                            \
      int row = (wq * 2 + i) * 8 + (lane >> 3);                                \
      async16(Kb + (size_t)((KT0) + row) * 64 +                                \
                  (((lane & 7) ^ (row & 7)) * 8),                              \
              &Kls[g][buf][(wq * 2 + i) * 512]);                               \
      async16(Vb + (size_t)row * 2048 + (KT0) +                                \
                  (((lane & 7) ^ (row & 7)) * 8),                              \
              &Vls[g][buf][(wq * 2 + i) * 512]);                               \
    }                                                                          \
  }

  const int tb = g * nT;
  STAGE(0, (tb + 0) * 64)
  STAGE(1, (tb + 1) * 64)

  const int qmax = qb + wq * 32 + 31;

  int cur = 0;
  for (int t = 0; t < nT; t++) {
    const int kt0 = (tb + t) * 64;
    if (t + 1 < nT) { asm volatile("s_waitcnt vmcnt(4)" ::: "memory"); }
    else            { asm volatile("s_waitcnt vmcnt(0)" ::: "memory"); }
    __builtin_amdgcn_s_barrier();

    if (kt0 <= qmax) {
      const u16* Kc = &Kls[g][cur][0];
      const u16* Vc = &Vls[g][cur][0];

      f32x16 s0, s1;
#pragma unroll
      for (int r = 0; r < 16; r++) { s0[r] = 0.f; s1[r] = 0.f; }
      __builtin_amdgcn_s_setprio(1);
#pragma unroll
      for (int ds = 0; ds < 4; ds++) {
        int cs = ((ds * 2 + hi2) ^ x7) * 8;
        bf16x8 kf0 = *(const bf16x8*)(Kc + q32 * 64 + cs);
        bf16x8 kf1 = *(const bf16x8*)(Kc + (32 + q32) * 64 + cs);
        s0 = mfma32(kf0, qf[ds], s0);
        s1 = mfma32(kf1, qf[ds], s1);
      }
      __builtin_amdgcn_s_setprio(0);

      bf16x8 vf0[4], vf1[4];
#pragma unroll
      for (int ksx = 0; ksx < 4; ksx++) {
        int sc = ((2 * ksx + hi2) ^ x7) * 8;
        vf0[ksx] = *(const bf16x8*)(Vc + q32 * 64 + sc);
        vf1[ksx] = *(const bf16x8*)(Vc + (32 + q32) * 64 + sc);
      }

      if (kt0 + 63 > qb + wq * 32) {
#pragma unroll
        for (int r = 0; r < 16; r++) {
          int kl = (r & 3) + 8 * (r >> 2) + 4 * hi2;
          if (kt0 + kl > qrow) s0[r] = -1e30f;
          if (kt0 + 32 + kl > qrow) s1[r] = -1e30f;
        }
      }

      float lpm = -1e30f;
#pragma unroll
      for (int r = 0; r < 16; r++) lpm = fmaxf(lpm, fmaxf(s0[r], s1[r]));
      if (__any(lpm > m_ + 8.f)) {
        float pm = fmaxf(lpm, __shfl_xor(lpm, 32));
        float mn = fmaxf(m_, pm);
        float corr = __builtin_amdgcn_exp2f(m_ - mn);
        m_ = mn;
#pragma unroll
        for (int r = 0; r < 16; r++) {
          o0[r] *= corr; o1[r] *= corr; lacc[r] *= corr;
        }
      }

#pragma unroll
      for (int r = 0; r < 16; r++) {
        s0[r] = __builtin_amdgcn_exp2f(s0[r] - m_);
        s1[r] = __builtin_amdgcn_exp2f(s1[r] - m_);
        lacc[r] += s0[r] + s1[r];
      }

      bf16x8 pb[4];
#pragma unroll
      for (int ksx = 0; ksx < 4; ksx++) {
        union { uint32_t u[4]; bf16x8 v; } pu;
        if (ksx < 2) {
          int rb = 8 * ksx;
          pu.u[0] = cvtpk(s0[rb + 0], s0[rb + 1]);
          pu.u[1] = cvtpk(s0[rb + 2], s0[rb + 3]);
          pu.u[2] = cvtpk(s0[rb + 4], s0[rb + 5]);
          pu.u[3] = cvtpk(s0[rb + 6], s0[rb + 7]);
        } else {
          int rb = 8 * (ksx - 2);
          pu.u[0] = cvtpk(s1[rb + 0], s1[rb + 1]);
          pu.u[1] = cvtpk(s1[rb + 2], s1[rb + 3]);
          pu.u[2] = cvtpk(s1[rb + 4], s1[rb + 5]);
          pu.u[3] = cvtpk(s1[rb + 6], s1[rb + 7]);
        }
        pb[ksx] = pu.v;
      }

      __builtin_amdgcn_s_setprio(1);
#pragma unroll
      for (int ksx = 0; ksx < 4; ksx++) {
        o0 = mfma32(vf0[ksx], pb[ksx], o0);
        o1 = mfma32(vf1[ksx], pb[ksx], o1);
      }
      __builtin_amdgcn_s_setprio(0);
    }

    __builtin_amdgcn_s_barrier();
    if (t + 2 < nT) STAGE(cur, (tb + t + 2) * 64)
    cur ^= 1;
  }

  float l_ = 0.f;
#pragma unroll
  for (int r = 0; r < 16; r++) l_ += lacc[r];
  l_ += __shfl_xor(l_, 32);

  __syncthreads();
  float* mb = (float*)&Kls[0][0][0] + wq * 2304;
  if (g == 1) {
#pragma unroll
    for (int m = 0; m < 4; m++) {
      f32x4 qa = {o0[4 * m + 0], o0[4 * m + 1], o0[4 * m + 2], o0[4 * m + 3]};
      f32x4 qb2 = {o1[4 * m + 0], o1[4 * m + 1], o1[4 * m + 2], o1[4 * m + 3]};
      *(f32x4*)(mb + m * 256 + (lane << 2)) = qa;
      *(f32x4*)(mb + (4 + m) * 256 + (lane << 2)) = qb2;
    }
    mb[2048 + (lane << 1) + 0] = m_;
    mb[2048 + (lane << 1) + 1] = l_;
  }
  __syncthreads();
  if (g == 0) {
    float m1 = mb[2048 + (lane << 1) + 0];
    float l1 = mb[2048 + (lane << 1) + 1];
    float mm = fmaxf(m_, m1);
    float cA = __builtin_amdgcn_exp2f(m_ - mm);
    float cB = __builtin_amdgcn_exp2f(m1 - mm);
    l_ = l_ * cA + l1 * cB;
#pragma unroll
    for (int m = 0; m < 4; m++) {
      f32x4 qa = *(const f32x4*)(mb + m * 256 + (lane << 2));
      f32x4 qb2 = *(const f32x4*)(mb + (4 + m) * 256 + (lane << 2));
#pragma unroll
      for (int jx = 0; jx < 4; jx++) {
        o0[4 * m + jx] = o0[4 * m + jx] * cA + qa[jx] * cB;
        o1[4 * m + jx] = o1[4 * m + jx] * cA + qb2[jx] * cB;
      }
    }

    const int b = bh >> 4, h = bh & 15;
    float inv = 1.f / l_;
    size_t base = ((size_t)(b * 2048 + qrow)) * 1024 + h * 64;
#pragma unroll
    for (int m = 0; m < 4; m++) {
      uint2 w0, w1;
      w0.x = cvtpk(o0[4 * m + 0] * inv, o0[4 * m + 1] * inv);
      w0.y = cvtpk(o0[4 * m + 2] * inv, o0[4 * m + 3] * inv);
      *(uint2*)(ctx + base + 8 * m + 4 * hi2) = w0;
      w1.x = cvtpk(o1[4 * m + 0] * inv, o1[4 * m + 1] * inv);
      w1.y = cvtpk(o1[4 * m + 2] * inv, o1[4 * m + 3] * inv);
      *(uint2*)(ctx + base + 32 + 8 * m + 4 * hi2) = w1;
    }
  }
}

// ---------------- launch ----------------

extern "C" void kernel_launch(void* const* d_in, const int* in_sizes, int n_in,
                              void* d_out, int out_size, void* d_ws, size_t ws_size,
                              hipStream_t stream) {
  const float* x  = (const float*)d_in[0];
  const float* Wq = (const float*)d_in[1];
  const float* bq = (const float*)d_in[2];
  const float* Wk = (const float*)d_in[3];
  const float* bk = (const float*)d_in[4];
  const float* Wv = (const float*)d_in[5];
  const float* bv = (const float*)d_in[6];
  const float* Wo = (const float*)d_in[7];
  const float* bo = (const float*)d_in[8];

  char* ws = (char*)d_ws;
  u16* xb  = (u16*)(ws);                    // [4096][1024] bf16, 8MB
  u16* wT  = (u16*)(ws + (8u << 20));       // 4 x [1024][1024] bf16, 8MB
  u16* qs  = (u16*)(ws + (16u << 20));      // [32][2048][64] bf16 (pre-scaled)
  u16* ks  = (u16*)(ws + (24u << 20));      // [32][2048][64] bf16
  u16* vts = (u16*)(ws + (32u << 20));      // [32][64][2048] bf16 (k-permuted)
  u16* ctx = (u16*)(ws + (40u << 20));      // [4096][1024] bf16

  cvt_kernel<<<5120, 256, 0, stream>>>(x, xb, Wq, Wk, Wv, Wo, wT);
  gemm_qkv_kernel<<<768, 256, 0, stream>>>(xb, wT, bq, bk, bv, qs, ks, vts);
  flash_kernel<<<512, 512, 0, stream>>>(qs, ks, vts, ctx);
  gemm_out_kernel<<<512, 256, 0, stream>>>(ctx, wT + 3 * (1u << 20), bo, (float*)d_out);
}